// Round 4
// baseline (3617.299 us; speedup 1.0000x reference)
//
#include <hip/hip_runtime.h>
#include <hip/hip_bf16.h>

#define HW 4096

// ---------------- d_out layout (fp32 elements) ----------------
// [0         .. 1,048,576)  q   [4][64][4096]   (scratch; feat_sum overwrites at end)
// [1,048,576 .. 3,145,728)  k   [2][4][64][4096]
// [3,145,728 .. 3,325,952)  wtp [2][256][352]   transposed proj weights
// [4,194,304 .. 8,388,608)  out1 (z, then mixed in place)
// [8,388,608 .. 12,582,912) out2
// d_ws is not used.
#define Q_OFF   0
#define K_OFF   1048576
#define WTP_OFF 3145728
#define O1_OFF  4194304

__device__ __forceinline__ void fma4(float4& a, float s, const float4& p) {
    a.x += s * p.x; a.y += s * p.y; a.z += s * p.z; a.w += s * p.w;
}

// ---------------- weight prep: proj weights -> [sel][c][co(352)] fp32, into d_out ----------------
__global__ __launch_bounds__(256) void wprep_proj(
    const float* __restrict__ wq1, const float* __restrict__ wk1, const float* __restrict__ wv1,
    const float* __restrict__ wq2, const float* __restrict__ wk2, const float* __restrict__ wv2,
    float* __restrict__ wtp) {
    int idx = blockIdx.x * 256 + threadIdx.x;        // 2*256*352 = 180,224 total
    if (idx >= 2 * 256 * 352) return;
    int sel = idx / 90112;
    int r   = idx - sel * 90112;
    int c   = r / 352;
    int co  = r - c * 352;
    const float* w; int row;
    if (co < 32)      { w = sel ? wq2 : wq1; row = co; }
    else if (co < 96) { w = sel ? wk2 : wk1; row = co - 32; }
    else              { w = sel ? wv2 : wv1; row = co - 96; }
    wtp[idx] = w[row * 256 + c];
}

// ---------------- projections: q|k = W x + b, tiled over 64 pixels ----------------
__global__ __launch_bounds__(256) void proj_kernel(
    const float* __restrict__ x1, const float* __restrict__ x2,
    const float* __restrict__ bq1, const float* __restrict__ bk1,
    const float* __restrict__ bq2, const float* __restrict__ bk2,
    float* __restrict__ dout) {
    __shared__ __align__(16) float xls[256][64];     // 64 KB
    const int tile = blockIdx.x, sel = blockIdx.y, b = blockIdx.z;
    const int n0 = tile * 64;
    const float* xb = (sel ? x2 : x1) + (size_t)b * 256 * HW;

    for (int i = threadIdx.x; i < 4096; i += 256) {  // 256 rows x 16 float4
        const int row = i >> 4, c4 = (i & 15) * 4;
        *(float4*)&xls[row][c4] = *(const float4*)(xb + (size_t)row * HW + n0 + c4);
    }
    __syncthreads();

    const int n   = threadIdx.x & 63;
    const int cog = __builtin_amdgcn_readfirstlane(threadIdx.x >> 6);   // 0..3, wave-uniform
    const float* bq = sel ? bq2 : bq1;
    const float* bk = sel ? bk2 : bk1;
    const float* wc = dout + WTP_OFF + (size_t)sel * 90112;   // [c][352]
    float* qout = dout + Q_OFF + (size_t)b * 64 * HW + (size_t)(sel ? 32 : 0) * HW;
    float* kout = dout + K_OFF + (size_t)sel * 1048576 + (size_t)b * 64 * HW;

    for (int blk = 0; blk < 3; ++blk) {              // 4 groups * 24 co = 96
        const int co0 = cog * 24 + blk * 8;          // never straddles the q/k split at 32
        const float* brow; float* obase; int r0;
        if (co0 < 32) { r0 = co0;      brow = bq; obase = qout; }
        else          { r0 = co0 - 32; brow = bk; obase = kout; }
        float acc[8];
        #pragma unroll
        for (int k = 0; k < 8; ++k) acc[k] = brow[r0 + k];
        #pragma unroll 4
        for (int c = 0; c < 256; ++c) {
            const float xv = xls[c][n];
            const float4 w0 = *(const float4*)(wc + (size_t)c * 352 + co0);
            const float4 w1 = *(const float4*)(wc + (size_t)c * 352 + co0 + 4);
            acc[0] += xv * w0.x; acc[1] += xv * w0.y; acc[2] += xv * w0.z; acc[3] += xv * w0.w;
            acc[4] += xv * w1.x; acc[5] += xv * w1.y; acc[6] += xv * w1.z; acc[7] += xv * w1.w;
        }
        float* orow = obase + (size_t)r0 * HW + n0 + n;
        #pragma unroll
        for (int k = 0; k < 8; ++k) orow[(size_t)k * HW] = acc[k];
    }
}

// ---------------- fused attention: scores + softmax + (x @ P^T)/l -> z ----------------
// wg = (qtile 64, branch, batch); 256 threads; 64 m-tiles of 64 keys.
// z[c][n] = sum_m x[c][m] p[m][n] / l[n]  -> out1/out2 slots of d_out.
__global__ __launch_bounds__(256) void attn_kernel(
    const float* __restrict__ in1, const float* __restrict__ in2,
    float* __restrict__ dout) {
    __shared__ __align__(16) float smem[4096];       // 16 KB: p[64][64]; reused for lsum/lfin

    const int qt = blockIdx.x, br = blockIdx.y, b = blockIdx.z;
    const int t  = threadIdx.x;

    const float* qg = dout + Q_OFF + (size_t)b * 64 * HW;
    const float* kg = dout + K_OFF + (size_t)br * 1048576 + (size_t)b * 64 * HW;
    const float* xg = (br ? in2 : in1) + (size_t)b * 256 * HW;   // PV source = input x
    float* zo = dout + O1_OFF + (size_t)br * 4194304 + (size_t)b * 256 * HW;

    const int sn = (t & 15) * 4;        // score mapping: 4 queries
    const int sm = (t >> 4) * 4;        //                4 keys
    const int nglob = qt * 64 + sn;
    const int pc = (t & 63) * 4;        // PV mapping: 4 channels
    const int pn = (t >> 6) * 16;       //             16 queries

    float l_part[4] = {0.f, 0.f, 0.f, 0.f};
    float4 acc[4][4];
    #pragma unroll
    for (int i = 0; i < 4; ++i)
        #pragma unroll
        for (int j = 0; j < 4; ++j) acc[i][j] = make_float4(0.f, 0.f, 0.f, 0.f);

    #pragma unroll 1
    for (int mt = 0; mt < 64; ++mt) {
        const int mg = mt * 64;
        // ---- scores: s(n,m) = sum_c q[c][n] * k[c][m], c = 0..63 ----
        float s[4][4];
        #pragma unroll
        for (int i = 0; i < 4; ++i)
            #pragma unroll
            for (int j = 0; j < 4; ++j) s[i][j] = 0.f;
        #pragma unroll 4
        for (int c = 0; c < 64; ++c) {
            const float4 qv = *(const float4*)(qg + (size_t)c * HW + nglob);
            const float4 kv = *(const float4*)(kg + (size_t)c * HW + mg + sm);
            const float qa[4] = { qv.x, qv.y, qv.z, qv.w };
            const float ka[4] = { kv.x, kv.y, kv.z, kv.w };
            #pragma unroll
            for (int i = 0; i < 4; ++i)
                #pragma unroll
                for (int j = 0; j < 4; ++j) s[i][j] += qa[i] * ka[j];
        }
        // |s| <= ~8 statistically; clamp keeps exp in range whatever the data
        #pragma unroll
        for (int i = 0; i < 4; ++i) {
            float rs = 0.f;
            #pragma unroll
            for (int j = 0; j < 4; ++j) {
                const float sc = fminf(fmaxf(s[i][j], -30.f), 30.f);
                const float p = __expf(sc);
                smem[(sm + j) * 64 + sn + i] = p;
                rs += p;
            }
            l_part[i] += rs;
        }
        __syncthreads();
        // ---- PV: acc[c][n] += x[c][m] * p[m][n] ----
        #pragma unroll 1
        for (int m8 = 0; m8 < 8; ++m8) {
            float vv[4][8];
            #pragma unroll
            for (int ci = 0; ci < 4; ++ci) {
                const float4 a0 = *(const float4*)(xg + (size_t)(pc + ci) * HW + mg + m8 * 8);
                const float4 a1 = *(const float4*)(xg + (size_t)(pc + ci) * HW + mg + m8 * 8 + 4);
                vv[ci][0] = a0.x; vv[ci][1] = a0.y; vv[ci][2] = a0.z; vv[ci][3] = a0.w;
                vv[ci][4] = a1.x; vv[ci][5] = a1.y; vv[ci][6] = a1.z; vv[ci][7] = a1.w;
            }
            #pragma unroll
            for (int jj = 0; jj < 8; ++jj) {
                const int m = m8 * 8 + jj;
                const float4* pr = (const float4*)(&smem[m * 64 + pn]);
                const float4 p0 = pr[0], p1 = pr[1], p2 = pr[2], p3 = pr[3];
                #pragma unroll
                for (int ci = 0; ci < 4; ++ci) {
                    const float vs = vv[ci][jj];
                    fma4(acc[ci][0], vs, p0);
                    fma4(acc[ci][1], vs, p1);
                    fma4(acc[ci][2], vs, p2);
                    fma4(acc[ci][3], vs, p3);
                }
            }
        }
        __syncthreads();
    }
    // ---- softmax denominator reduction (overlay on smem; p is dead) ----
    float* lsum = smem;                  // [64][17]
    float* lfin = smem + 64 * 17;        // [64]
    #pragma unroll
    for (int i = 0; i < 4; ++i) lsum[(sn + i) * 17 + (t >> 4)] = l_part[i];
    __syncthreads();
    if (t < 64) {
        float sum = 0.f;
        #pragma unroll
        for (int g = 0; g < 16; ++g) sum += lsum[t * 17 + g];
        lfin[t] = sum;
    }
    __syncthreads();
    // ---- write z = acc / l ----
    float rl[16];
    #pragma unroll
    for (int nn = 0; nn < 16; ++nn) rl[nn] = 1.0f / lfin[pn + nn];
    #pragma unroll
    for (int ci = 0; ci < 4; ++ci) {
        const size_t base = (size_t)(pc + ci) * HW + qt * 64 + pn;
        #pragma unroll
        for (int g = 0; g < 4; ++g) {
            const float4 a = acc[ci][g];
            float4 o;
            o.x = a.x * rl[g * 4 + 0];
            o.y = a.y * rl[g * 4 + 1];
            o.z = a.z * rl[g * 4 + 2];
            o.w = a.w * rl[g * 4 + 3];
            *(float4*)(zo + base + g * 4) = o;
        }
    }
}

// ---------------- mix: out = gamma * (Wv z + bv) + x, in place over z ----------------
// softmax rows sum to 1 -> bias contributes exactly bv.
__global__ __launch_bounds__(256) void mix_kernel(
    const float* __restrict__ in1, const float* __restrict__ in2,
    const float* __restrict__ bv1, const float* __restrict__ bv2,
    const float* __restrict__ gamma_p,
    float* __restrict__ dout) {
    __shared__ __align__(16) float zl[256][64];      // 64 KB
    const int tile = blockIdx.x, sel = blockIdx.y, b = blockIdx.z;
    const int n0 = tile * 64;
    float* zg = dout + O1_OFF + (size_t)sel * 4194304 + (size_t)b * 256 * HW;

    for (int i = threadIdx.x; i < 4096; i += 256) {
        const int row = i >> 4, c4 = (i & 15) * 4;
        *(float4*)&zl[row][c4] = *(const float4*)(zg + (size_t)row * HW + n0 + c4);
    }
    __syncthreads();                                  // whole tile staged -> in-place safe

    const int n   = threadIdx.x & 63;
    const int cog = __builtin_amdgcn_readfirstlane(threadIdx.x >> 6);
    const float* xg = (sel ? in2 : in1) + (size_t)b * 256 * HW;
    const float* bv = sel ? bv2 : bv1;
    const float gamma = gamma_p[0];
    const float* wc = dout + WTP_OFF + (size_t)sel * 90112 + 96; // v columns start at 96

    for (int blk = 0; blk < 8; ++blk) {               // 4 groups * 64 co = 256
        const int o0 = cog * 64 + blk * 8;
        float acc[8];
        #pragma unroll
        for (int k = 0; k < 8; ++k) acc[k] = bv[o0 + k];
        #pragma unroll 4
        for (int c = 0; c < 256; ++c) {
            const float zv = zl[c][n];
            const float4 w0 = *(const float4*)(wc + (size_t)c * 352 + o0);
            const float4 w1 = *(const float4*)(wc + (size_t)c * 352 + o0 + 4);
            acc[0] += zv * w0.x; acc[1] += zv * w0.y; acc[2] += zv * w0.z; acc[3] += zv * w0.w;
            acc[4] += zv * w1.x; acc[5] += zv * w1.y; acc[6] += zv * w1.z; acc[7] += zv * w1.w;
        }
        #pragma unroll
        for (int k = 0; k < 8; ++k) {
            const size_t idx = (size_t)(o0 + k) * HW + n0 + n;
            zg[idx] = gamma * acc[k] + xg[idx];
        }
    }
}

// ---------------- 3x3 conv (512->256) + BN + ReLU, weights staged from native layout ----------------
__global__ __launch_bounds__(256) void conv_kernel(
    const float* __restrict__ wcat,                  // [256][512][3][3] fp32 (native)
    const float* __restrict__ bn_scale, const float* __restrict__ bn_bias,
    const float* __restrict__ bn_mean,  const float* __restrict__ bn_var,
    float* __restrict__ dout) {
    __shared__ float xl[16][6][66];                  // 25,344 B
    __shared__ __align__(16) float wl[16][9][16];    //  9,216 B  [ci][dd][o]
    const int sp = blockIdx.x, ot = blockIdx.y, b = blockIdx.z;
    const int h0 = sp * 4;
    const int t  = threadIdx.x;
    const int y  = t >> 6, x = t & 63;
    const int so = t >> 4, sci = t & 15;             // staging: o-sub, ci-sub

    float acc[16];
    #pragma unroll
    for (int k = 0; k < 16; ++k) acc[k] = 0.f;

    #pragma unroll 1
    for (int ci0 = 0; ci0 < 512; ci0 += 16) {
        const float* src = dout + O1_OFF + (size_t)(ci0 < 256 ? 0 : 1) * 4194304
                         + (size_t)b * 1048576 + (size_t)(ci0 & 255) * HW;
        __syncthreads();
        for (int idx = t; idx < 16 * 6 * 66; idx += 256) {
            const int ci  = idx / 396;
            const int rem = idx - ci * 396;
            const int yy  = rem / 66;
            const int xx  = rem - yy * 66;
            const int hh = h0 + yy - 1, ww = xx - 1;
            float v = 0.f;
            if (hh >= 0 && hh < 64 && ww >= 0 && ww < 64)
                v = src[(size_t)ci * HW + hh * 64 + ww];
            xl[ci][yy][xx] = v;
        }
        {   // stage weights: w[ot*16+so][ci0+sci][0..8] -> wl[sci][dd][so]
            const float* wsrc = wcat + ((size_t)(ot * 16 + so) * 512 + ci0 + sci) * 9;
            #pragma unroll
            for (int dd = 0; dd < 9; ++dd) wl[sci][dd][so] = wsrc[dd];
        }
        __syncthreads();
        #pragma unroll 1
        for (int ci = 0; ci < 16; ++ci) {
            #pragma unroll
            for (int dy = 0; dy < 3; ++dy) {
                #pragma unroll
                for (int dx = 0; dx < 3; ++dx) {
                    const float xv = xl[ci][y + dy][x + dx];
                    const float4* wp = (const float4*)&wl[ci][dy * 3 + dx][0];
                    const float4 w0 = wp[0], w1 = wp[1], w2 = wp[2], w3 = wp[3];
                    fma4(*(float4*)&acc[0],  xv, w0);
                    fma4(*(float4*)&acc[4],  xv, w1);
                    fma4(*(float4*)&acc[8],  xv, w2);
                    fma4(*(float4*)&acc[12], xv, w3);
                }
            }
        }
    }
    const int px = (h0 + y) * 64 + x;
    #pragma unroll
    for (int k = 0; k < 16; ++k) {
        const int o = ot * 16 + k;
        const float inv = bn_scale[o] * __frsqrt_rn(bn_var[o] + 1e-5f);
        float r = acc[k] * inv + (bn_bias[o] - bn_mean[o] * inv);
        r = r > 0.f ? r : 0.f;
        dout[((size_t)b * 256 + o) * HW + px] = r;
    }
}

extern "C" void kernel_launch(void* const* d_in, const int* in_sizes, int n_in,
                              void* d_out, int out_size, void* d_ws, size_t ws_size,
                              hipStream_t stream) {
    (void)in_sizes; (void)n_in; (void)out_size; (void)d_ws; (void)ws_size;
    const float* x1   = (const float*)d_in[0];
    const float* x2   = (const float*)d_in[1];
    const float* wq1  = (const float*)d_in[2];
    const float* bq1  = (const float*)d_in[3];
    const float* wk1  = (const float*)d_in[4];
    const float* bk1  = (const float*)d_in[5];
    const float* wv1  = (const float*)d_in[6];
    const float* bv1  = (const float*)d_in[7];
    const float* wq2  = (const float*)d_in[8];
    const float* bq2  = (const float*)d_in[9];
    const float* wk2  = (const float*)d_in[10];
    const float* bk2  = (const float*)d_in[11];
    const float* wv2  = (const float*)d_in[12];
    const float* bv2  = (const float*)d_in[13];
    const float* gma  = (const float*)d_in[14];
    const float* wcat = (const float*)d_in[15];
    const float* bns  = (const float*)d_in[16];
    const float* bnb  = (const float*)d_in[17];
    const float* bnm  = (const float*)d_in[18];
    const float* bnv  = (const float*)d_in[19];

    float* out = (float*)d_out;

    wprep_proj<<<704, 256, 0, stream>>>(wq1, wk1, wv1, wq2, wk2, wv2, out + WTP_OFF);
    proj_kernel<<<dim3(64, 2, 4), 256, 0, stream>>>(x1, x2, bq1, bk1, bq2, bk2, out);
    attn_kernel<<<dim3(64, 2, 4), 256, 0, stream>>>(x1, x2, out);
    mix_kernel<<<dim3(64, 2, 4), 256, 0, stream>>>(x1, x2, bv1, bv2, gma, out);
    conv_kernel<<<dim3(16, 16, 4), 256, 0, stream>>>(wcat, bns, bnb, bnm, bnv, out);
}

// Round 5
// 1444.139 us; speedup vs baseline: 2.5048x; 2.5048x over previous
//
#include <hip/hip_runtime.h>
#include <hip/hip_bf16.h>

#define HW 4096

// ---------------- d_out layout ----------------
// bf16 elements:
//   [0         .. 1,048,576)  q_t [4][4096 n][64 c]   (c: 0..31 br1-q, 32..63 br2-q)
//   [1,048,576 .. 3,145,728)  k_t [2][4][4096 m][64 c]
// fp32 elements:
//   [1,572,864 .. 1,753,088)  wtp [2][256][352] transposed proj weights
//   [4,194,304 .. 8,388,608)  out1 (z, then mixed in place)
//   [8,388,608 .. 12,582,912) out2
// Scratch region [0..4,194,304 floats) is overwritten by conv output at the end.
#define KT_OFF   1048576        // bf16 elements
#define WTP_OFF  1572864        // float elements
#define O1_OFF   4194304        // float elements

typedef short v8s  __attribute__((ext_vector_type(8)));
typedef float v16f __attribute__((ext_vector_type(16)));

#define LSTR 72                 // LDS row stride (bf16) -> 144 B, 16B-aligned, conflict-free

__device__ __forceinline__ unsigned short f2b(float f) {   // fp32 -> bf16 RNE
    unsigned u = __float_as_uint(f);
    return (unsigned short)((u + 0x7fffu + ((u >> 16) & 1u)) >> 16);
}
__device__ __forceinline__ float b2f_raw(unsigned short u) {
    return __uint_as_float((unsigned)u << 16);
}
__device__ __forceinline__ void fma4(float4& a, float s, const float4& p) {
    a.x += s * p.x; a.y += s * p.y; a.z += s * p.z; a.w += s * p.w;
}

// ---------------- weight prep: proj weights -> [sel][c][co(352)] fp32 ----------------
__global__ __launch_bounds__(256) void wprep_proj(
    const float* __restrict__ wq1, const float* __restrict__ wk1, const float* __restrict__ wv1,
    const float* __restrict__ wq2, const float* __restrict__ wk2, const float* __restrict__ wv2,
    float* __restrict__ wtp) {
    int idx = blockIdx.x * 256 + threadIdx.x;        // 2*256*352 = 180,224 total
    if (idx >= 2 * 256 * 352) return;
    int sel = idx / 90112;
    int r   = idx - sel * 90112;
    int c   = r / 352;
    int co  = r - c * 352;
    const float* w; int row;
    if (co < 32)      { w = sel ? wq2 : wq1; row = co; }
    else if (co < 96) { w = sel ? wk2 : wk1; row = co - 32; }
    else              { w = sel ? wv2 : wv1; row = co - 96; }
    wtp[idx] = w[row * 256 + c];
}

// ---------------- projections: q|k = W x + b -> bf16 transposed q_t/k_t ----------------
__global__ __launch_bounds__(256) void proj_kernel(
    const float* __restrict__ x1, const float* __restrict__ x2,
    const float* __restrict__ bq1, const float* __restrict__ bk1,
    const float* __restrict__ bq2, const float* __restrict__ bk2,
    float* __restrict__ dout) {
    __shared__ __align__(16) float xls[256][64];     // 64 KB
    const int tile = blockIdx.x, sel = blockIdx.y, b = blockIdx.z;
    const int n0 = tile * 64;
    const float* xb = (sel ? x2 : x1) + (size_t)b * 256 * HW;

    for (int i = threadIdx.x; i < 4096; i += 256) {
        const int row = i >> 4, c4 = (i & 15) * 4;
        *(float4*)&xls[row][c4] = *(const float4*)(xb + (size_t)row * HW + n0 + c4);
    }
    __syncthreads();

    const int n   = threadIdx.x & 63;
    const int cog = __builtin_amdgcn_readfirstlane(threadIdx.x >> 6);   // 0..3, wave-uniform
    const float* bq = sel ? bq2 : bq1;
    const float* bk = sel ? bk2 : bk1;
    const float* wc = dout + WTP_OFF + (size_t)sel * 90112;   // [c][352]
    unsigned short* qtg = (unsigned short*)dout + (size_t)b * HW * 64;
    unsigned short* ktg = (unsigned short*)dout + KT_OFF + (size_t)(sel * 4 + b) * HW * 64;

    for (int blk = 0; blk < 3; ++blk) {              // 4 groups * 24 co = 96
        const int co0 = cog * 24 + blk * 8;          // never straddles the q/k split at 32
        float acc[8];
        const float* brow; int r0; bool isq;
        if (co0 < 32) { r0 = co0;      brow = bq; isq = true;  }
        else          { r0 = co0 - 32; brow = bk; isq = false; }
        #pragma unroll
        for (int k = 0; k < 8; ++k) acc[k] = brow[r0 + k];
        #pragma unroll 4
        for (int c = 0; c < 256; ++c) {
            const float xv = xls[c][n];
            const float4 w0 = *(const float4*)(wc + (size_t)c * 352 + co0);
            const float4 w1 = *(const float4*)(wc + (size_t)c * 352 + co0 + 4);
            acc[0] += xv * w0.x; acc[1] += xv * w0.y; acc[2] += xv * w0.z; acc[3] += xv * w0.w;
            acc[4] += xv * w1.x; acc[5] += xv * w1.y; acc[6] += xv * w1.z; acc[7] += xv * w1.w;
        }
        unsigned short pk[8];
        #pragma unroll
        for (int k = 0; k < 8; ++k) pk[k] = f2b(acc[k]);
        unsigned short* dst = isq ? (qtg + (size_t)(n0 + n) * 64 + sel * 32 + r0)
                                  : (ktg + (size_t)(n0 + n) * 64 + r0);
        *(uint4*)dst = *(const uint4*)pk;            // 16B store (offset multiple of 8 elems)
    }
}

// ---------------- MFMA attention: S=Q^T K, P=exp(S), z = X P / l ----------------
// wg = (qtile 64, branch, batch); 4 waves; 64 m-tiles of 64 keys.
__global__ __launch_bounds__(256, 2) void attn_kernel(
    const float* __restrict__ in1, const float* __restrict__ in2,
    float* __restrict__ dout) {
    __shared__ __align__(16) unsigned short qlds[64][LSTR];    // [n][c]
    __shared__ __align__(16) unsigned short klds[64][LSTR];    // [m][c]
    __shared__ __align__(16) unsigned short plds[64][LSTR];    // [n][m]
    __shared__ __align__(16) unsigned short xlds[256][LSTR];   // [c][m]
    __shared__ float lsum[64][4];
    __shared__ float lfin[64];

    const int qt = blockIdx.x, br = blockIdx.y, b = blockIdx.z;
    const int t = threadIdx.x;
    const int w = t >> 6, lane = t & 63, h = lane >> 5, l32 = lane & 31;

    const unsigned short* qtg = (const unsigned short*)dout + (size_t)b * HW * 64;
    const unsigned short* ktg = (const unsigned short*)dout + KT_OFF + (size_t)(br * 4 + b) * HW * 64;
    const float* xg = (br ? in2 : in1) + (size_t)b * 256 * HW;
    float* zo = dout + O1_OFF + (size_t)br * 4194304 + (size_t)b * 256 * HW;

    // stage Q tile once: q_t[qt*64+row][c]
    for (int i = t; i < 512; i += 256) {
        const int row = i >> 3, c8 = (i & 7) * 8;
        *(uint4*)&qlds[row][c8] = *(const uint4*)(qtg + (size_t)(qt * 64 + row) * 64 + c8);
    }

    const int nsub = (w & 1) * 32, msub = (w >> 1) * 32;   // QK^T tile of this wave
    const int c0 = w * 64;                                  // PV c-rows of this wave
    const int koff = h * 8;                                 // k-dim element offset within frag

    v16f a00, a01, a10, a11;                                // PV accumulators (c-sub x n-sub)
    #pragma unroll
    for (int i = 0; i < 16; ++i) { a00[i] = 0.f; a01[i] = 0.f; a10[i] = 0.f; a11[i] = 0.f; }
    float lrun = 0.f;                                       // row-sum partial (n = t>>2, quarter t&3)
    const int nl2 = t >> 2, q16 = (t & 3) * 16;

    uint4  kreg[2];
    float4 xreg[16];
    // prefetch tile 0
    #pragma unroll
    for (int j = 0; j < 2; ++j) {
        const int i = t + j * 256, row = i >> 3, c8 = (i & 7) * 8;
        kreg[j] = *(const uint4*)(ktg + (size_t)row * 64 + c8);
    }
    #pragma unroll
    for (int j = 0; j < 16; ++j) {
        const int i = t + j * 256, c = i >> 4, m4 = (i & 15) * 4;
        xreg[j] = *(const float4*)(xg + (size_t)c * HW + m4);
    }

    #pragma unroll 1
    for (int mt = 0; mt < 64; ++mt) {
        __syncthreads();                         // prev PV done with klds/xlds/plds
        // ---- commit staged tile to LDS ----
        #pragma unroll
        for (int j = 0; j < 2; ++j) {
            const int i = t + j * 256, row = i >> 3, c8 = (i & 7) * 8;
            *(uint4*)&klds[row][c8] = kreg[j];
        }
        #pragma unroll
        for (int j = 0; j < 16; ++j) {
            const int i = t + j * 256, c = i >> 4, m4 = (i & 15) * 4;
            uint2 pk;
            pk.x = (unsigned)f2b(xreg[j].x) | ((unsigned)f2b(xreg[j].y) << 16);
            pk.y = (unsigned)f2b(xreg[j].z) | ((unsigned)f2b(xreg[j].w) << 16);
            *(uint2*)&xlds[c][m4] = pk;
        }
        __syncthreads();                         // tiles ready
        // ---- S = Q^T K (one 32x32 tile per wave, K-dim = 64 channels) ----
        v16f s;
        #pragma unroll
        for (int i = 0; i < 16; ++i) s[i] = 0.f;
        #pragma unroll
        for (int ks = 0; ks < 4; ++ks) {
            const v8s aq = *(const v8s*)&qlds[nsub + l32][ks * 16 + koff];
            const v8s bk = *(const v8s*)&klds[msub + l32][ks * 16 + koff];
            s = __builtin_amdgcn_mfma_f32_32x32x16_bf16(aq, bk, s, 0, 0, 0);
        }
        // ---- P = exp(S) -> plds[n][m] bf16 ----
        #pragma unroll
        for (int r = 0; r < 16; ++r) {
            const int nl = nsub + (r & 3) + 8 * (r >> 2) + 4 * h;
            const int ml = msub + l32;
            const float e = __expf(fminf(fmaxf(s[r], -30.f), 30.f));
            plds[nl][ml] = f2b(e);
        }
        // ---- prefetch next tile (hidden under PV) ----
        if (mt < 63) {
            const int mg = (mt + 1) * 64;
            #pragma unroll
            for (int j = 0; j < 2; ++j) {
                const int i = t + j * 256, row = i >> 3, c8 = (i & 7) * 8;
                kreg[j] = *(const uint4*)(ktg + (size_t)(mg + row) * 64 + c8);
            }
            #pragma unroll
            for (int j = 0; j < 16; ++j) {
                const int i = t + j * 256, c = i >> 4, m4 = (i & 15) * 4;
                xreg[j] = *(const float4*)(xg + (size_t)c * HW + mg + m4);
            }
        }
        __syncthreads();                         // plds ready
        // ---- row-sum accumulation from bf16 P (consistent with PV inputs) ----
        {
            const v8s r0 = *(const v8s*)&plds[nl2][q16];
            const v8s r1 = *(const v8s*)&plds[nl2][q16 + 8];
            float su = 0.f;
            #pragma unroll
            for (int e = 0; e < 8; ++e)
                su += b2f_raw((unsigned short)r0[e]) + b2f_raw((unsigned short)r1[e]);
            lrun += su;
        }
        // ---- PV: acc[c][n] += X[c][m] P[m][n], K-dim = 64 keys ----
        #pragma unroll
        for (int ks = 0; ks < 4; ++ks) {
            const int mo = ks * 16 + koff;
            const v8s xa0 = *(const v8s*)&xlds[c0 + l32][mo];
            const v8s xa1 = *(const v8s*)&xlds[c0 + 32 + l32][mo];
            const v8s pb0 = *(const v8s*)&plds[l32][mo];
            const v8s pb1 = *(const v8s*)&plds[32 + l32][mo];
            a00 = __builtin_amdgcn_mfma_f32_32x32x16_bf16(xa0, pb0, a00, 0, 0, 0);
            a01 = __builtin_amdgcn_mfma_f32_32x32x16_bf16(xa0, pb1, a01, 0, 0, 0);
            a10 = __builtin_amdgcn_mfma_f32_32x32x16_bf16(xa1, pb0, a10, 0, 0, 0);
            a11 = __builtin_amdgcn_mfma_f32_32x32x16_bf16(xa1, pb1, a11, 0, 0, 0);
        }
    }
    // ---- softmax denominators ----
    __syncthreads();
    lsum[nl2][t & 3] = lrun;
    __syncthreads();
    if (t < 64) lfin[t] = 1.0f / (lsum[t][0] + lsum[t][1] + lsum[t][2] + lsum[t][3]);
    __syncthreads();
    const float rl0 = lfin[l32];
    const float rl1 = lfin[32 + l32];
    // ---- write z = acc / l ----
    const int ncol = qt * 64;
    #pragma unroll
    for (int r = 0; r < 16; ++r) {
        const int c = c0 + (r & 3) + 8 * (r >> 2) + 4 * h;
        zo[(size_t)c * HW + ncol + l32]             = a00[r] * rl0;
        zo[(size_t)c * HW + ncol + 32 + l32]        = a01[r] * rl1;
        zo[(size_t)(c + 32) * HW + ncol + l32]      = a10[r] * rl0;
        zo[(size_t)(c + 32) * HW + ncol + 32 + l32] = a11[r] * rl1;
    }
}

// ---------------- mix: out = gamma * (Wv z + bv) + x, in place over z ----------------
__global__ __launch_bounds__(256) void mix_kernel(
    const float* __restrict__ in1, const float* __restrict__ in2,
    const float* __restrict__ bv1, const float* __restrict__ bv2,
    const float* __restrict__ gamma_p,
    float* __restrict__ dout) {
    __shared__ __align__(16) float zl[256][64];      // 64 KB
    const int tile = blockIdx.x, sel = blockIdx.y, b = blockIdx.z;
    const int n0 = tile * 64;
    float* zg = dout + O1_OFF + (size_t)sel * 4194304 + (size_t)b * 256 * HW;

    for (int i = threadIdx.x; i < 4096; i += 256) {
        const int row = i >> 4, c4 = (i & 15) * 4;
        *(float4*)&zl[row][c4] = *(const float4*)(zg + (size_t)row * HW + n0 + c4);
    }
    __syncthreads();                                  // whole tile staged -> in-place safe

    const int n   = threadIdx.x & 63;
    const int cog = __builtin_amdgcn_readfirstlane(threadIdx.x >> 6);
    const float* xg = (sel ? in2 : in1) + (size_t)b * 256 * HW;
    const float* bv = sel ? bv2 : bv1;
    const float gamma = gamma_p[0];
    const float* wc = dout + WTP_OFF + (size_t)sel * 90112 + 96; // v columns start at 96

    for (int blk = 0; blk < 8; ++blk) {               // 4 groups * 64 co = 256
        const int o0 = cog * 64 + blk * 8;
        float acc[8];
        #pragma unroll
        for (int k = 0; k < 8; ++k) acc[k] = bv[o0 + k];
        #pragma unroll 4
        for (int c = 0; c < 256; ++c) {
            const float zv = zl[c][n];
            const float4 w0 = *(const float4*)(wc + (size_t)c * 352 + o0);
            const float4 w1 = *(const float4*)(wc + (size_t)c * 352 + o0 + 4);
            acc[0] += zv * w0.x; acc[1] += zv * w0.y; acc[2] += zv * w0.z; acc[3] += zv * w0.w;
            acc[4] += zv * w1.x; acc[5] += zv * w1.y; acc[6] += zv * w1.z; acc[7] += zv * w1.w;
        }
        #pragma unroll
        for (int k = 0; k < 8; ++k) {
            const size_t idx = (size_t)(o0 + k) * HW + n0 + n;
            zg[idx] = gamma * acc[k] + xg[idx];
        }
    }
}

// ---------------- 3x3 conv (512->256) + BN + ReLU ----------------
__global__ __launch_bounds__(256) void conv_kernel(
    const float* __restrict__ wcat,                  // [256][512][3][3] fp32 (native)
    const float* __restrict__ bn_scale, const float* __restrict__ bn_bias,
    const float* __restrict__ bn_mean,  const float* __restrict__ bn_var,
    float* __restrict__ dout) {
    __shared__ float xl[16][6][66];                  // 25,344 B
    __shared__ __align__(16) float wl[16][9][16];    //  9,216 B  [ci][dd][o]
    const int sp = blockIdx.x, ot = blockIdx.y, b = blockIdx.z;
    const int h0 = sp * 4;
    const int t  = threadIdx.x;
    const int y  = t >> 6, x = t & 63;
    const int so = t >> 4, sci = t & 15;             // staging: o-sub, ci-sub

    float acc[16];
    #pragma unroll
    for (int k = 0; k < 16; ++k) acc[k] = 0.f;

    #pragma unroll 1
    for (int ci0 = 0; ci0 < 512; ci0 += 16) {
        const float* src = dout + O1_OFF + (size_t)(ci0 < 256 ? 0 : 1) * 4194304
                         + (size_t)b * 1048576 + (size_t)(ci0 & 255) * HW;
        __syncthreads();
        for (int idx = t; idx < 16 * 6 * 66; idx += 256) {
            const int ci  = idx / 396;
            const int rem = idx - ci * 396;
            const int yy  = rem / 66;
            const int xx  = rem - yy * 66;
            const int hh = h0 + yy - 1, ww = xx - 1;
            float v = 0.f;
            if (hh >= 0 && hh < 64 && ww >= 0 && ww < 64)
                v = src[(size_t)ci * HW + hh * 64 + ww];
            xl[ci][yy][xx] = v;
        }
        {   // stage weights: w[ot*16+so][ci0+sci][0..8] -> wl[sci][dd][so]
            const float* wsrc = wcat + ((size_t)(ot * 16 + so) * 512 + ci0 + sci) * 9;
            #pragma unroll
            for (int dd = 0; dd < 9; ++dd) wl[sci][dd][so] = wsrc[dd];
        }
        __syncthreads();
        #pragma unroll 1
        for (int ci = 0; ci < 16; ++ci) {
            #pragma unroll
            for (int dy = 0; dy < 3; ++dy) {
                #pragma unroll
                for (int dx = 0; dx < 3; ++dx) {
                    const float xv = xl[ci][y + dy][x + dx];
                    const float4* wp = (const float4*)&wl[ci][dy * 3 + dx][0];
                    const float4 w0 = wp[0], w1 = wp[1], w2 = wp[2], w3 = wp[3];
                    fma4(*(float4*)&acc[0],  xv, w0);
                    fma4(*(float4*)&acc[4],  xv, w1);
                    fma4(*(float4*)&acc[8],  xv, w2);
                    fma4(*(float4*)&acc[12], xv, w3);
                }
            }
        }
    }
    const int px = (h0 + y) * 64 + x;
    #pragma unroll
    for (int k = 0; k < 16; ++k) {
        const int o = ot * 16 + k;
        const float inv = bn_scale[o] * __frsqrt_rn(bn_var[o] + 1e-5f);
        float r = acc[k] * inv + (bn_bias[o] - bn_mean[o] * inv);
        r = r > 0.f ? r : 0.f;
        dout[((size_t)b * 256 + o) * HW + px] = r;
    }
}

extern "C" void kernel_launch(void* const* d_in, const int* in_sizes, int n_in,
                              void* d_out, int out_size, void* d_ws, size_t ws_size,
                              hipStream_t stream) {
    (void)in_sizes; (void)n_in; (void)out_size; (void)d_ws; (void)ws_size;
    const float* x1   = (const float*)d_in[0];
    const float* x2   = (const float*)d_in[1];
    const float* wq1  = (const float*)d_in[2];
    const float* bq1  = (const float*)d_in[3];
    const float* wk1  = (const float*)d_in[4];
    const float* bk1  = (const float*)d_in[5];
    const float* wv1  = (const float*)d_in[6];
    const float* bv1  = (const float*)d_in[7];
    const float* wq2  = (const float*)d_in[8];
    const float* bq2  = (const float*)d_in[9];
    const float* wk2  = (const float*)d_in[10];
    const float* bk2  = (const float*)d_in[11];
    const float* wv2  = (const float*)d_in[12];
    const float* bv2  = (const float*)d_in[13];
    const float* gma  = (const float*)d_in[14];
    const float* wcat = (const float*)d_in[15];
    const float* bns  = (const float*)d_in[16];
    const float* bnb  = (const float*)d_in[17];
    const float* bnm  = (const float*)d_in[18];
    const float* bnv  = (const float*)d_in[19];

    float* out = (float*)d_out;

    wprep_proj<<<704, 256, 0, stream>>>(wq1, wk1, wv1, wq2, wk2, wv2, out + WTP_OFF);
    proj_kernel<<<dim3(64, 2, 4), 256, 0, stream>>>(x1, x2, bq1, bk1, bq2, bk2, out);
    attn_kernel<<<dim3(64, 2, 4), 256, 0, stream>>>(x1, x2, out);
    mix_kernel<<<dim3(64, 2, 4), 256, 0, stream>>>(x1, x2, bv1, bv2, gma, out);
    conv_kernel<<<dim3(16, 16, 4), 256, 0, stream>>>(wcat, bns, bnb, bnm, bnv, out);
}

// Round 6
// 993.667 us; speedup vs baseline: 3.6404x; 1.4533x over previous
//
#include <hip/hip_runtime.h>
#include <hip/hip_bf16.h>

#define HW 4096

// ---------------- d_out layout ----------------
// bf16 elements:
//   [0         .. 1,048,576)  q_t [4][4096 n][64 c]   (c: 0..31 br1-q, 32..63 br2-q)
//   [1,048,576 .. 3,145,728)  k_t [2][4][4096 m][64 c]
// fp32 elements:
//   [1,572,864 .. 1,753,088)  wtp [2][256][352] transposed proj weights
//   [4,194,304 .. 8,388,608)  out1 (z, then mixed in place)
//   [8,388,608 .. 12,582,912) out2
// Scratch region [0..4,194,304 floats) is overwritten by conv output at the end.
#define KT_OFF   1048576        // bf16 elements
#define WTP_OFF  1572864        // float elements
#define O1_OFF   4194304        // float elements

typedef short v8s  __attribute__((ext_vector_type(8)));
typedef float v16f __attribute__((ext_vector_type(16)));

#define LSTR 72                 // attention LDS row stride (bf16)
#define CPAD 20                 // conv LDS ci-stride (bf16): 40 B, bank-stride 10 -> 2-way (free)

__device__ __forceinline__ unsigned short f2b(float f) {   // fp32 -> bf16 RNE
    unsigned u = __float_as_uint(f);
    return (unsigned short)((u + 0x7fffu + ((u >> 16) & 1u)) >> 16);
}
__device__ __forceinline__ float b2f_raw(unsigned short u) {
    return __uint_as_float((unsigned)u << 16);
}
__device__ __forceinline__ void fma4(float4& a, float s, const float4& p) {
    a.x += s * p.x; a.y += s * p.y; a.z += s * p.z; a.w += s * p.w;
}
__device__ __forceinline__ v8s load8(const unsigned short* p) {  // 8 bf16 via two b64
    union { uint2 u[2]; v8s v; } t;
    t.u[0] = *(const uint2*)p;
    t.u[1] = *(const uint2*)(p + 4);
    return t.v;
}

// ---------------- weight prep: proj weights -> [sel][c][co(352)] fp32 ----------------
__global__ __launch_bounds__(256) void wprep_proj(
    const float* __restrict__ wq1, const float* __restrict__ wk1, const float* __restrict__ wv1,
    const float* __restrict__ wq2, const float* __restrict__ wk2, const float* __restrict__ wv2,
    float* __restrict__ wtp) {
    int idx = blockIdx.x * 256 + threadIdx.x;        // 2*256*352 = 180,224 total
    if (idx >= 2 * 256 * 352) return;
    int sel = idx / 90112;
    int r   = idx - sel * 90112;
    int c   = r / 352;
    int co  = r - c * 352;
    const float* w; int row;
    if (co < 32)      { w = sel ? wq2 : wq1; row = co; }
    else if (co < 96) { w = sel ? wk2 : wk1; row = co - 32; }
    else              { w = sel ? wv2 : wv1; row = co - 96; }
    wtp[idx] = w[row * 256 + c];
}

// ---------------- projections: q|k = W x + b -> bf16 transposed q_t/k_t ----------------
__global__ __launch_bounds__(256) void proj_kernel(
    const float* __restrict__ x1, const float* __restrict__ x2,
    const float* __restrict__ bq1, const float* __restrict__ bk1,
    const float* __restrict__ bq2, const float* __restrict__ bk2,
    float* __restrict__ dout) {
    __shared__ __align__(16) float xls[256][64];     // 64 KB
    const int tile = blockIdx.x, sel = blockIdx.y, b = blockIdx.z;
    const int n0 = tile * 64;
    const float* xb = (sel ? x2 : x1) + (size_t)b * 256 * HW;

    for (int i = threadIdx.x; i < 4096; i += 256) {
        const int row = i >> 4, c4 = (i & 15) * 4;
        *(float4*)&xls[row][c4] = *(const float4*)(xb + (size_t)row * HW + n0 + c4);
    }
    __syncthreads();

    const int n   = threadIdx.x & 63;
    const int cog = __builtin_amdgcn_readfirstlane(threadIdx.x >> 6);   // 0..3, wave-uniform
    const float* bq = sel ? bq2 : bq1;
    const float* bk = sel ? bk2 : bk1;
    const float* wc = dout + WTP_OFF + (size_t)sel * 90112;   // [c][352]
    unsigned short* qtg = (unsigned short*)dout + (size_t)b * HW * 64;
    unsigned short* ktg = (unsigned short*)dout + KT_OFF + (size_t)(sel * 4 + b) * HW * 64;

    for (int blk = 0; blk < 3; ++blk) {              // 4 groups * 24 co = 96
        const int co0 = cog * 24 + blk * 8;          // never straddles the q/k split at 32
        float acc[8];
        const float* brow; int r0; bool isq;
        if (co0 < 32) { r0 = co0;      brow = bq; isq = true;  }
        else          { r0 = co0 - 32; brow = bk; isq = false; }
        #pragma unroll
        for (int k = 0; k < 8; ++k) acc[k] = brow[r0 + k];
        #pragma unroll 4
        for (int c = 0; c < 256; ++c) {
            const float xv = xls[c][n];
            const float4 w0 = *(const float4*)(wc + (size_t)c * 352 + co0);
            const float4 w1 = *(const float4*)(wc + (size_t)c * 352 + co0 + 4);
            acc[0] += xv * w0.x; acc[1] += xv * w0.y; acc[2] += xv * w0.z; acc[3] += xv * w0.w;
            acc[4] += xv * w1.x; acc[5] += xv * w1.y; acc[6] += xv * w1.z; acc[7] += xv * w1.w;
        }
        unsigned short pk[8];
        #pragma unroll
        for (int k = 0; k < 8; ++k) pk[k] = f2b(acc[k]);
        unsigned short* dst = isq ? (qtg + (size_t)(n0 + n) * 64 + sel * 32 + r0)
                                  : (ktg + (size_t)(n0 + n) * 64 + r0);
        *(uint4*)dst = *(const uint4*)pk;            // 16B store
    }
}

// ---------------- MFMA attention: S=Q^T K, P=exp(S), z = X P / l ----------------
__global__ __launch_bounds__(256, 2) void attn_kernel(
    const float* __restrict__ in1, const float* __restrict__ in2,
    float* __restrict__ dout) {
    __shared__ __align__(16) unsigned short qlds[64][LSTR];    // [n][c]
    __shared__ __align__(16) unsigned short klds[64][LSTR];    // [m][c]
    __shared__ __align__(16) unsigned short plds[64][LSTR];    // [n][m]
    __shared__ __align__(16) unsigned short xlds[256][LSTR];   // [c][m]
    __shared__ float lsum[64][4];
    __shared__ float lfin[64];

    const int qt = blockIdx.x, br = blockIdx.y, b = blockIdx.z;
    const int t = threadIdx.x;
    const int w = t >> 6, lane = t & 63, h = lane >> 5, l32 = lane & 31;

    const unsigned short* qtg = (const unsigned short*)dout + (size_t)b * HW * 64;
    const unsigned short* ktg = (const unsigned short*)dout + KT_OFF + (size_t)(br * 4 + b) * HW * 64;
    const float* xg = (br ? in2 : in1) + (size_t)b * 256 * HW;
    float* zo = dout + O1_OFF + (size_t)br * 4194304 + (size_t)b * 256 * HW;

    for (int i = t; i < 512; i += 256) {
        const int row = i >> 3, c8 = (i & 7) * 8;
        *(uint4*)&qlds[row][c8] = *(const uint4*)(qtg + (size_t)(qt * 64 + row) * 64 + c8);
    }

    const int nsub = (w & 1) * 32, msub = (w >> 1) * 32;
    const int c0 = w * 64;
    const int koff = h * 8;

    v16f a00, a01, a10, a11;
    #pragma unroll
    for (int i = 0; i < 16; ++i) { a00[i] = 0.f; a01[i] = 0.f; a10[i] = 0.f; a11[i] = 0.f; }
    float lrun = 0.f;
    const int nl2 = t >> 2, q16 = (t & 3) * 16;

    uint4  kreg[2];
    float4 xreg[16];
    #pragma unroll
    for (int j = 0; j < 2; ++j) {
        const int i = t + j * 256, row = i >> 3, c8 = (i & 7) * 8;
        kreg[j] = *(const uint4*)(ktg + (size_t)row * 64 + c8);
    }
    #pragma unroll
    for (int j = 0; j < 16; ++j) {
        const int i = t + j * 256, c = i >> 4, m4 = (i & 15) * 4;
        xreg[j] = *(const float4*)(xg + (size_t)c * HW + m4);
    }

    #pragma unroll 1
    for (int mt = 0; mt < 64; ++mt) {
        __syncthreads();
        #pragma unroll
        for (int j = 0; j < 2; ++j) {
            const int i = t + j * 256, row = i >> 3, c8 = (i & 7) * 8;
            *(uint4*)&klds[row][c8] = kreg[j];
        }
        #pragma unroll
        for (int j = 0; j < 16; ++j) {
            const int i = t + j * 256, c = i >> 4, m4 = (i & 15) * 4;
            uint2 pk;
            pk.x = (unsigned)f2b(xreg[j].x) | ((unsigned)f2b(xreg[j].y) << 16);
            pk.y = (unsigned)f2b(xreg[j].z) | ((unsigned)f2b(xreg[j].w) << 16);
            *(uint2*)&xlds[c][m4] = pk;
        }
        __syncthreads();
        v16f s;
        #pragma unroll
        for (int i = 0; i < 16; ++i) s[i] = 0.f;
        #pragma unroll
        for (int ks = 0; ks < 4; ++ks) {
            const v8s aq = *(const v8s*)&qlds[nsub + l32][ks * 16 + koff];
            const v8s bk = *(const v8s*)&klds[msub + l32][ks * 16 + koff];
            s = __builtin_amdgcn_mfma_f32_32x32x16_bf16(aq, bk, s, 0, 0, 0);
        }
        #pragma unroll
        for (int r = 0; r < 16; ++r) {
            const int nl = nsub + (r & 3) + 8 * (r >> 2) + 4 * h;
            const int ml = msub + l32;
            const float e = __expf(fminf(fmaxf(s[r], -30.f), 30.f));
            plds[nl][ml] = f2b(e);
        }
        if (mt < 63) {
            const int mg = (mt + 1) * 64;
            #pragma unroll
            for (int j = 0; j < 2; ++j) {
                const int i = t + j * 256, row = i >> 3, c8 = (i & 7) * 8;
                kreg[j] = *(const uint4*)(ktg + (size_t)(mg + row) * 64 + c8);
            }
            #pragma unroll
            for (int j = 0; j < 16; ++j) {
                const int i = t + j * 256, c = i >> 4, m4 = (i & 15) * 4;
                xreg[j] = *(const float4*)(xg + (size_t)c * HW + mg + m4);
            }
        }
        __syncthreads();
        {
            const v8s r0 = *(const v8s*)&plds[nl2][q16];
            const v8s r1 = *(const v8s*)&plds[nl2][q16 + 8];
            float su = 0.f;
            #pragma unroll
            for (int e = 0; e < 8; ++e)
                su += b2f_raw((unsigned short)r0[e]) + b2f_raw((unsigned short)r1[e]);
            lrun += su;
        }
        #pragma unroll
        for (int ks = 0; ks < 4; ++ks) {
            const int mo = ks * 16 + koff;
            const v8s xa0 = *(const v8s*)&xlds[c0 + l32][mo];
            const v8s xa1 = *(const v8s*)&xlds[c0 + 32 + l32][mo];
            const v8s pb0 = *(const v8s*)&plds[l32][mo];
            const v8s pb1 = *(const v8s*)&plds[32 + l32][mo];
            a00 = __builtin_amdgcn_mfma_f32_32x32x16_bf16(xa0, pb0, a00, 0, 0, 0);
            a01 = __builtin_amdgcn_mfma_f32_32x32x16_bf16(xa0, pb1, a01, 0, 0, 0);
            a10 = __builtin_amdgcn_mfma_f32_32x32x16_bf16(xa1, pb0, a10, 0, 0, 0);
            a11 = __builtin_amdgcn_mfma_f32_32x32x16_bf16(xa1, pb1, a11, 0, 0, 0);
        }
    }
    __syncthreads();
    lsum[nl2][t & 3] = lrun;
    __syncthreads();
    if (t < 64) lfin[t] = 1.0f / (lsum[t][0] + lsum[t][1] + lsum[t][2] + lsum[t][3]);
    __syncthreads();
    const float rl0 = lfin[l32];
    const float rl1 = lfin[32 + l32];
    const int ncol = qt * 64;
    #pragma unroll
    for (int r = 0; r < 16; ++r) {
        const int c = c0 + (r & 3) + 8 * (r >> 2) + 4 * h;
        zo[(size_t)c * HW + ncol + l32]             = a00[r] * rl0;
        zo[(size_t)c * HW + ncol + 32 + l32]        = a01[r] * rl1;
        zo[(size_t)(c + 32) * HW + ncol + l32]      = a10[r] * rl0;
        zo[(size_t)(c + 32) * HW + ncol + 32 + l32] = a11[r] * rl1;
    }
}

// ---------------- mix: out = gamma * (Wv z + bv) + x, in place over z ----------------
__global__ __launch_bounds__(256) void mix_kernel(
    const float* __restrict__ in1, const float* __restrict__ in2,
    const float* __restrict__ bv1, const float* __restrict__ bv2,
    const float* __restrict__ gamma_p,
    float* __restrict__ dout) {
    __shared__ __align__(16) float zl[256][64];      // 64 KB
    const int tile = blockIdx.x, sel = blockIdx.y, b = blockIdx.z;
    const int n0 = tile * 64;
    float* zg = dout + O1_OFF + (size_t)sel * 4194304 + (size_t)b * 256 * HW;

    for (int i = threadIdx.x; i < 4096; i += 256) {
        const int row = i >> 4, c4 = (i & 15) * 4;
        *(float4*)&zl[row][c4] = *(const float4*)(zg + (size_t)row * HW + n0 + c4);
    }
    __syncthreads();                                  // whole tile staged -> in-place safe

    const int n   = threadIdx.x & 63;
    const int cog = __builtin_amdgcn_readfirstlane(threadIdx.x >> 6);
    const float* xg = (sel ? in2 : in1) + (size_t)b * 256 * HW;
    const float* bv = sel ? bv2 : bv1;
    const float gamma = gamma_p[0];
    const float* wc = dout + WTP_OFF + (size_t)sel * 90112 + 96; // v columns start at 96

    for (int blk = 0; blk < 8; ++blk) {               // 4 groups * 64 co = 256
        const int o0 = cog * 64 + blk * 8;
        float acc[8];
        #pragma unroll
        for (int k = 0; k < 8; ++k) acc[k] = bv[o0 + k];
        #pragma unroll 4
        for (int c = 0; c < 256; ++c) {
            const float zv = zl[c][n];
            const float4 w0 = *(const float4*)(wc + (size_t)c * 352 + o0);
            const float4 w1 = *(const float4*)(wc + (size_t)c * 352 + o0 + 4);
            acc[0] += zv * w0.x; acc[1] += zv * w0.y; acc[2] += zv * w0.z; acc[3] += zv * w0.w;
            acc[4] += zv * w1.x; acc[5] += zv * w1.y; acc[6] += zv * w1.z; acc[7] += zv * w1.w;
        }
        #pragma unroll
        for (int k = 0; k < 8; ++k) {
            const size_t idx = (size_t)(o0 + k) * HW + n0 + n;
            zg[idx] = gamma * acc[k] + xg[idx];
        }
    }
}

// ---------------- MFMA 3x3 conv (512->256) + BN + ReLU ----------------
// Implicit GEMM: 9 shifted 1x1 GEMMs; K = ci in chunks of 16.
// Block: 64 o x 128 px (2 image rows); 4 waves x 2 tiles of 32x32.
__global__ __launch_bounds__(256) void conv_kernel(
    const float* __restrict__ wcat,                  // [256 o][512 ci][3][3] fp32 (native)
    const float* __restrict__ bn_scale, const float* __restrict__ bn_bias,
    const float* __restrict__ bn_mean,  const float* __restrict__ bn_var,
    float* __restrict__ dout) {
    __shared__ __align__(16) unsigned short xl[4][66][CPAD];   // [row][col][ci] 10,560 B
    __shared__ __align__(16) unsigned short wl[9][64][CPAD];   // [tap][o][ci]  23,040 B

    const int pt = blockIdx.x;                       // 0..31 -> rows h0, h0+1
    const int ot = blockIdx.y;                       // 0..3
    const int b  = blockIdx.z;
    const int h0 = pt * 2;
    const int t  = threadIdx.x;
    const int w  = t >> 6, lane = t & 63, h = lane >> 5, l32 = lane & 31;
    const int osub = (w & 1) * 32;                   // wave's o sub-tile
    const int ps0  = (w >> 1) * 64;                  // wave's px subs: ps0, ps0+32

    // BN constants per accumulator register (D row = o via C/D formula)
    float inv[16], add[16];
    #pragma unroll
    for (int r = 0; r < 16; ++r) {
        const int o_g = ot * 64 + osub + (r & 3) + 8 * (r >> 2) + 4 * h;
        const float iv = bn_scale[o_g] * __frsqrt_rn(bn_var[o_g] + 1e-5f);
        inv[r] = iv;
        add[r] = bn_bias[o_g] - bn_mean[o_g] * iv;
    }

    v16f acc0, acc1;
    #pragma unroll
    for (int i = 0; i < 16; ++i) { acc0[i] = 0.f; acc1[i] = 0.f; }

    #pragma unroll 1
    for (int ci0 = 0; ci0 < 512; ci0 += 16) {
        const float* src = dout + O1_OFF + (size_t)(ci0 < 256 ? 0 : 1) * 4194304
                         + (size_t)b * 1048576 + (size_t)(ci0 & 255) * HW;
        const float* wsrc = wcat + (size_t)(ot * 64) * 4608 + (size_t)ci0 * 9;
        __syncthreads();
        // ---- stage X transposed: [row][col][ci], zero halo ----
        for (int i = t; i < 2112; i += 256) {        // 4 rows * 66 cols * 8 ci-pairs
            const int col = i % 66;
            const int rem = i / 66;
            const int row = rem & 3;
            const int cp  = rem >> 2;
            const int hh = h0 + row - 1, ww = col - 1;
            float v0 = 0.f, v1 = 0.f;
            if (hh >= 0 && hh < 64 && ww >= 0 && ww < 64) {
                v0 = src[(size_t)(2 * cp) * HW + hh * 64 + ww];
                v1 = src[(size_t)(2 * cp + 1) * HW + hh * 64 + ww];
            }
            *(unsigned*)&xl[row][col][2 * cp] = (unsigned)f2b(v0) | ((unsigned)f2b(v1) << 16);
        }
        // ---- stage W transposed: [tap][o][ci]; source contiguous 144 floats per o ----
        for (int i = t; i < 9216; i += 256) {        // 64 o * 144 (ci*9+tap)
            const int o  = i / 144;
            const int r  = i - o * 144;
            const int ci = r / 9, tap = r - ci * 9;
            wl[tap][o][ci] = f2b(wsrc[(size_t)o * 4608 + r]);
        }
        __syncthreads();
        // ---- 9 taps x (K=16) MFMA ----
        #pragma unroll
        for (int dy = 0; dy < 3; ++dy) {
            #pragma unroll
            for (int dx = 0; dx < 3; ++dx) {
                const v8s af = load8(&wl[dy * 3 + dx][osub + l32][h * 8]);
                const int n0 = ps0 + l32, n1 = ps0 + 32 + l32;
                const v8s b0 = load8(&xl[(n0 >> 6) + dy][(n0 & 63) + dx][h * 8]);
                const v8s b1 = load8(&xl[(n1 >> 6) + dy][(n1 & 63) + dx][h * 8]);
                acc0 = __builtin_amdgcn_mfma_f32_32x32x16_bf16(af, b0, acc0, 0, 0, 0);
                acc1 = __builtin_amdgcn_mfma_f32_32x32x16_bf16(af, b1, acc1, 0, 0, 0);
            }
        }
    }
    // ---- epilogue: BN + ReLU + store ----
    const int px0 = ps0 + l32, px1 = ps0 + 32 + l32;
    const size_t gpx0 = (size_t)(h0 + (px0 >> 6)) * 64 + (px0 & 63);
    const size_t gpx1 = (size_t)(h0 + (px1 >> 6)) * 64 + (px1 & 63);
    #pragma unroll
    for (int r = 0; r < 16; ++r) {
        const int o_g = ot * 64 + osub + (r & 3) + 8 * (r >> 2) + 4 * h;
        const size_t obase = ((size_t)b * 256 + o_g) * HW;
        float v0 = acc0[r] * inv[r] + add[r];
        float v1 = acc1[r] * inv[r] + add[r];
        v0 = v0 > 0.f ? v0 : 0.f;
        v1 = v1 > 0.f ? v1 : 0.f;
        dout[obase + gpx0] = v0;
        dout[obase + gpx1] = v1;
    }
}

extern "C" void kernel_launch(void* const* d_in, const int* in_sizes, int n_in,
                              void* d_out, int out_size, void* d_ws, size_t ws_size,
                              hipStream_t stream) {
    (void)in_sizes; (void)n_in; (void)out_size; (void)d_ws; (void)ws_size;
    const float* x1   = (const float*)d_in[0];
    const float* x2   = (const float*)d_in[1];
    const float* wq1  = (const float*)d_in[2];
    const float* bq1  = (const float*)d_in[3];
    const float* wk1  = (const float*)d_in[4];
    const float* bk1  = (const float*)d_in[5];
    const float* wv1  = (const float*)d_in[6];
    const float* bv1  = (const float*)d_in[7];
    const float* wq2  = (const float*)d_in[8];
    const float* bq2  = (const float*)d_in[9];
    const float* wk2  = (const float*)d_in[10];
    const float* bk2  = (const float*)d_in[11];
    const float* wv2  = (const float*)d_in[12];
    const float* bv2  = (const float*)d_in[13];
    const float* gma  = (const float*)d_in[14];
    const float* wcat = (const float*)d_in[15];
    const float* bns  = (const float*)d_in[16];
    const float* bnb  = (const float*)d_in[17];
    const float* bnm  = (const float*)d_in[18];
    const float* bnv  = (const float*)d_in[19];

    float* out = (float*)d_out;

    wprep_proj<<<704, 256, 0, stream>>>(wq1, wk1, wv1, wq2, wk2, wv2, out + WTP_OFF);
    proj_kernel<<<dim3(64, 2, 4), 256, 0, stream>>>(x1, x2, bq1, bk1, bq2, bk2, out);
    attn_kernel<<<dim3(64, 2, 4), 256, 0, stream>>>(x1, x2, out);
    mix_kernel<<<dim3(64, 2, 4), 256, 0, stream>>>(x1, x2, bv1, bv2, gma, out);
    conv_kernel<<<dim3(32, 4, 4), 256, 0, stream>>>(wcat, bns, bnb, bnm, bnv, out);
}

// Round 7
// 754.689 us; speedup vs baseline: 4.7931x; 1.3167x over previous
//
#include <hip/hip_runtime.h>
#include <hip/hip_bf16.h>

#define HW 4096

// ---------------- d_out layout ----------------
// bf16 elements:
//   [0         .. 1,048,576)  q_t [4][4096 n][64 c]   (c: 0..31 br1-q, 32..63 br2-q)
//   [1,048,576 .. 3,145,728)  k_t [2][4][4096 m][64 c]
// fp32 elements:
//   [1,572,864 .. 1,753,088)  wtp [2][256][352] transposed proj weights
//   [4,194,304 .. 8,388,608)  out1 (z, then mixed in place)
//   [8,388,608 .. 12,582,912) out2
// Scratch region [0..4,194,304 floats) is overwritten by conv output at the end.
// d_ws (bf16): wt_conv [32 chunk][9 tap][256 o][16 ci] = 1,179,648 elems = 2,359,296 B
#define KT_OFF   1048576        // bf16 elements
#define WTP_OFF  1572864        // float elements
#define O1_OFF   4194304        // float elements

typedef short v8s  __attribute__((ext_vector_type(8)));
typedef float v16f __attribute__((ext_vector_type(16)));

#define LSTR 72                 // attention LDS row stride (bf16)
#define CPAD 20                 // conv LDS ci-stride (bf16): 40 B, bank-stride 10 -> ~2-way

__device__ __forceinline__ unsigned short f2b(float f) {   // fp32 -> bf16 RNE
    unsigned u = __float_as_uint(f);
    return (unsigned short)((u + 0x7fffu + ((u >> 16) & 1u)) >> 16);
}
__device__ __forceinline__ float b2f_raw(unsigned short u) {
    return __uint_as_float((unsigned)u << 16);
}
__device__ __forceinline__ void fma4(float4& a, float s, const float4& p) {
    a.x += s * p.x; a.y += s * p.y; a.z += s * p.z; a.w += s * p.w;
}
__device__ __forceinline__ v8s load8(const unsigned short* p) {  // 8 bf16 via two b64
    union { uint2 u[2]; v8s v; } t;
    t.u[0] = *(const uint2*)p;
    t.u[1] = *(const uint2*)(p + 4);
    return t.v;
}

// ---------------- weight prep: proj weights -> [sel][c][co(352)] fp32 ----------------
__global__ __launch_bounds__(256) void wprep_proj(
    const float* __restrict__ wq1, const float* __restrict__ wk1, const float* __restrict__ wv1,
    const float* __restrict__ wq2, const float* __restrict__ wk2, const float* __restrict__ wv2,
    float* __restrict__ wtp) {
    int idx = blockIdx.x * 256 + threadIdx.x;        // 2*256*352 = 180,224 total
    if (idx >= 2 * 256 * 352) return;
    int sel = idx / 90112;
    int r   = idx - sel * 90112;
    int c   = r / 352;
    int co  = r - c * 352;
    const float* w; int row;
    if (co < 32)      { w = sel ? wq2 : wq1; row = co; }
    else if (co < 96) { w = sel ? wk2 : wk1; row = co - 32; }
    else              { w = sel ? wv2 : wv1; row = co - 96; }
    wtp[idx] = w[row * 256 + c];
}

// ---------------- weight prep: conv w [256 o][512 ci][3][3] fp32 -> bf16 [chunk][tap][o][ci16] ----------------
__global__ __launch_bounds__(256) void wprep_convw(const float* __restrict__ wcat,
                                                   unsigned short* __restrict__ wt) {
    int i = blockIdx.x * 256 + threadIdx.x;          // 32*9*256*16 = 1,179,648 total
    if (i >= 32 * 9 * 256 * 16) return;
    const int ci_l = i & 15;
    const int o    = (i >> 4) & 255;
    const int t2   = i >> 12;                        // chunk*9 + tap
    const int tap  = t2 % 9;
    const int chunk = t2 / 9;
    wt[i] = f2b(wcat[((size_t)o * 512 + chunk * 16 + ci_l) * 9 + tap]);
}

// ---------------- projections: q|k = W x + b -> bf16 transposed q_t/k_t ----------------
__global__ __launch_bounds__(256) void proj_kernel(
    const float* __restrict__ x1, const float* __restrict__ x2,
    const float* __restrict__ bq1, const float* __restrict__ bk1,
    const float* __restrict__ bq2, const float* __restrict__ bk2,
    float* __restrict__ dout) {
    __shared__ __align__(16) float xls[256][64];     // 64 KB
    const int tile = blockIdx.x, sel = blockIdx.y, b = blockIdx.z;
    const int n0 = tile * 64;
    const float* xb = (sel ? x2 : x1) + (size_t)b * 256 * HW;

    for (int i = threadIdx.x; i < 4096; i += 256) {
        const int row = i >> 4, c4 = (i & 15) * 4;
        *(float4*)&xls[row][c4] = *(const float4*)(xb + (size_t)row * HW + n0 + c4);
    }
    __syncthreads();

    const int n   = threadIdx.x & 63;
    const int cog = __builtin_amdgcn_readfirstlane(threadIdx.x >> 6);   // 0..3, wave-uniform
    const float* bq = sel ? bq2 : bq1;
    const float* bk = sel ? bk2 : bk1;
    const float* wc = dout + WTP_OFF + (size_t)sel * 90112;   // [c][352]
    unsigned short* qtg = (unsigned short*)dout + (size_t)b * HW * 64;
    unsigned short* ktg = (unsigned short*)dout + KT_OFF + (size_t)(sel * 4 + b) * HW * 64;

    for (int blk = 0; blk < 3; ++blk) {              // 4 groups * 24 co = 96
        const int co0 = cog * 24 + blk * 8;          // never straddles the q/k split at 32
        float acc[8];
        const float* brow; int r0; bool isq;
        if (co0 < 32) { r0 = co0;      brow = bq; isq = true;  }
        else          { r0 = co0 - 32; brow = bk; isq = false; }
        #pragma unroll
        for (int k = 0; k < 8; ++k) acc[k] = brow[r0 + k];
        #pragma unroll 4
        for (int c = 0; c < 256; ++c) {
            const float xv = xls[c][n];
            const float4 w0 = *(const float4*)(wc + (size_t)c * 352 + co0);
            const float4 w1 = *(const float4*)(wc + (size_t)c * 352 + co0 + 4);
            acc[0] += xv * w0.x; acc[1] += xv * w0.y; acc[2] += xv * w0.z; acc[3] += xv * w0.w;
            acc[4] += xv * w1.x; acc[5] += xv * w1.y; acc[6] += xv * w1.z; acc[7] += xv * w1.w;
        }
        unsigned short pk[8];
        #pragma unroll
        for (int k = 0; k < 8; ++k) pk[k] = f2b(acc[k]);
        unsigned short* dst = isq ? (qtg + (size_t)(n0 + n) * 64 + sel * 32 + r0)
                                  : (ktg + (size_t)(n0 + n) * 64 + r0);
        *(uint4*)dst = *(const uint4*)pk;            // 16B store
    }
}

// ---------------- MFMA attention: S=Q^T K, P=exp(S), z = X P / l ----------------
__global__ __launch_bounds__(256, 2) void attn_kernel(
    const float* __restrict__ in1, const float* __restrict__ in2,
    float* __restrict__ dout) {
    __shared__ __align__(16) unsigned short qlds[64][LSTR];    // [n][c]
    __shared__ __align__(16) unsigned short klds[64][LSTR];    // [m][c]
    __shared__ __align__(16) unsigned short plds[64][LSTR];    // [n][m]
    __shared__ __align__(16) unsigned short xlds[256][LSTR];   // [c][m]
    __shared__ float lsum[64][4];
    __shared__ float lfin[64];

    const int qt = blockIdx.x, br = blockIdx.y, b = blockIdx.z;
    const int t = threadIdx.x;
    const int w = t >> 6, lane = t & 63, h = lane >> 5, l32 = lane & 31;

    const unsigned short* qtg = (const unsigned short*)dout + (size_t)b * HW * 64;
    const unsigned short* ktg = (const unsigned short*)dout + KT_OFF + (size_t)(br * 4 + b) * HW * 64;
    const float* xg = (br ? in2 : in1) + (size_t)b * 256 * HW;
    float* zo = dout + O1_OFF + (size_t)br * 4194304 + (size_t)b * 256 * HW;

    for (int i = t; i < 512; i += 256) {
        const int row = i >> 3, c8 = (i & 7) * 8;
        *(uint4*)&qlds[row][c8] = *(const uint4*)(qtg + (size_t)(qt * 64 + row) * 64 + c8);
    }

    const int nsub = (w & 1) * 32, msub = (w >> 1) * 32;
    const int c0 = w * 64;
    const int koff = h * 8;

    v16f a00, a01, a10, a11;
    #pragma unroll
    for (int i = 0; i < 16; ++i) { a00[i] = 0.f; a01[i] = 0.f; a10[i] = 0.f; a11[i] = 0.f; }
    float lrun = 0.f;
    const int nl2 = t >> 2, q16 = (t & 3) * 16;

    uint4  kreg[2];
    float4 xreg[16];
    #pragma unroll
    for (int j = 0; j < 2; ++j) {
        const int i = t + j * 256, row = i >> 3, c8 = (i & 7) * 8;
        kreg[j] = *(const uint4*)(ktg + (size_t)row * 64 + c8);
    }
    #pragma unroll
    for (int j = 0; j < 16; ++j) {
        const int i = t + j * 256, c = i >> 4, m4 = (i & 15) * 4;
        xreg[j] = *(const float4*)(xg + (size_t)c * HW + m4);
    }

    #pragma unroll 1
    for (int mt = 0; mt < 64; ++mt) {
        __syncthreads();
        #pragma unroll
        for (int j = 0; j < 2; ++j) {
            const int i = t + j * 256, row = i >> 3, c8 = (i & 7) * 8;
            *(uint4*)&klds[row][c8] = kreg[j];
        }
        #pragma unroll
        for (int j = 0; j < 16; ++j) {
            const int i = t + j * 256, c = i >> 4, m4 = (i & 15) * 4;
            uint2 pk;
            pk.x = (unsigned)f2b(xreg[j].x) | ((unsigned)f2b(xreg[j].y) << 16);
            pk.y = (unsigned)f2b(xreg[j].z) | ((unsigned)f2b(xreg[j].w) << 16);
            *(uint2*)&xlds[c][m4] = pk;
        }
        __syncthreads();
        v16f s;
        #pragma unroll
        for (int i = 0; i < 16; ++i) s[i] = 0.f;
        #pragma unroll
        for (int ks = 0; ks < 4; ++ks) {
            const v8s aq = *(const v8s*)&qlds[nsub + l32][ks * 16 + koff];
            const v8s bk = *(const v8s*)&klds[msub + l32][ks * 16 + koff];
            s = __builtin_amdgcn_mfma_f32_32x32x16_bf16(aq, bk, s, 0, 0, 0);
        }
        #pragma unroll
        for (int r = 0; r < 16; ++r) {
            const int nl = nsub + (r & 3) + 8 * (r >> 2) + 4 * h;
            const int ml = msub + l32;
            const float e = __expf(fminf(fmaxf(s[r], -30.f), 30.f));
            plds[nl][ml] = f2b(e);
        }
        if (mt < 63) {
            const int mg = (mt + 1) * 64;
            #pragma unroll
            for (int j = 0; j < 2; ++j) {
                const int i = t + j * 256, row = i >> 3, c8 = (i & 7) * 8;
                kreg[j] = *(const uint4*)(ktg + (size_t)(mg + row) * 64 + c8);
            }
            #pragma unroll
            for (int j = 0; j < 16; ++j) {
                const int i = t + j * 256, c = i >> 4, m4 = (i & 15) * 4;
                xreg[j] = *(const float4*)(xg + (size_t)c * HW + mg + m4);
            }
        }
        __syncthreads();
        {
            const v8s r0 = *(const v8s*)&plds[nl2][q16];
            const v8s r1 = *(const v8s*)&plds[nl2][q16 + 8];
            float su = 0.f;
            #pragma unroll
            for (int e = 0; e < 8; ++e)
                su += b2f_raw((unsigned short)r0[e]) + b2f_raw((unsigned short)r1[e]);
            lrun += su;
        }
        #pragma unroll
        for (int ks = 0; ks < 4; ++ks) {
            const int mo = ks * 16 + koff;
            const v8s xa0 = *(const v8s*)&xlds[c0 + l32][mo];
            const v8s xa1 = *(const v8s*)&xlds[c0 + 32 + l32][mo];
            const v8s pb0 = *(const v8s*)&plds[l32][mo];
            const v8s pb1 = *(const v8s*)&plds[32 + l32][mo];
            a00 = __builtin_amdgcn_mfma_f32_32x32x16_bf16(xa0, pb0, a00, 0, 0, 0);
            a01 = __builtin_amdgcn_mfma_f32_32x32x16_bf16(xa0, pb1, a01, 0, 0, 0);
            a10 = __builtin_amdgcn_mfma_f32_32x32x16_bf16(xa1, pb0, a10, 0, 0, 0);
            a11 = __builtin_amdgcn_mfma_f32_32x32x16_bf16(xa1, pb1, a11, 0, 0, 0);
        }
    }
    __syncthreads();
    lsum[nl2][t & 3] = lrun;
    __syncthreads();
    if (t < 64) lfin[t] = 1.0f / (lsum[t][0] + lsum[t][1] + lsum[t][2] + lsum[t][3]);
    __syncthreads();
    const float rl0 = lfin[l32];
    const float rl1 = lfin[32 + l32];
    const int ncol = qt * 64;
    #pragma unroll
    for (int r = 0; r < 16; ++r) {
        const int c = c0 + (r & 3) + 8 * (r >> 2) + 4 * h;
        zo[(size_t)c * HW + ncol + l32]             = a00[r] * rl0;
        zo[(size_t)c * HW + ncol + 32 + l32]        = a01[r] * rl1;
        zo[(size_t)(c + 32) * HW + ncol + l32]      = a10[r] * rl0;
        zo[(size_t)(c + 32) * HW + ncol + 32 + l32] = a11[r] * rl1;
    }
}

// ---------------- mix: out = gamma * (Wv z + bv) + x, in place over z ----------------
__global__ __launch_bounds__(256) void mix_kernel(
    const float* __restrict__ in1, const float* __restrict__ in2,
    const float* __restrict__ bv1, const float* __restrict__ bv2,
    const float* __restrict__ gamma_p,
    float* __restrict__ dout) {
    __shared__ __align__(16) float zl[256][64];      // 64 KB
    const int tile = blockIdx.x, sel = blockIdx.y, b = blockIdx.z;
    const int n0 = tile * 64;
    float* zg = dout + O1_OFF + (size_t)sel * 4194304 + (size_t)b * 256 * HW;

    for (int i = threadIdx.x; i < 4096; i += 256) {
        const int row = i >> 4, c4 = (i & 15) * 4;
        *(float4*)&zl[row][c4] = *(const float4*)(zg + (size_t)row * HW + n0 + c4);
    }
    __syncthreads();                                  // whole tile staged -> in-place safe

    const int n   = threadIdx.x & 63;
    const int cog = __builtin_amdgcn_readfirstlane(threadIdx.x >> 6);
    const float* xg = (sel ? in2 : in1) + (size_t)b * 256 * HW;
    const float* bv = sel ? bv2 : bv1;
    const float gamma = gamma_p[0];
    const float* wc = dout + WTP_OFF + (size_t)sel * 90112 + 96; // v columns start at 96

    for (int blk = 0; blk < 8; ++blk) {               // 4 groups * 64 co = 256
        const int o0 = cog * 64 + blk * 8;
        float acc[8];
        #pragma unroll
        for (int k = 0; k < 8; ++k) acc[k] = bv[o0 + k];
        #pragma unroll 4
        for (int c = 0; c < 256; ++c) {
            const float zv = zl[c][n];
            const float4 w0 = *(const float4*)(wc + (size_t)c * 352 + o0);
            const float4 w1 = *(const float4*)(wc + (size_t)c * 352 + o0 + 4);
            acc[0] += zv * w0.x; acc[1] += zv * w0.y; acc[2] += zv * w0.z; acc[3] += zv * w0.w;
            acc[4] += zv * w1.x; acc[5] += zv * w1.y; acc[6] += zv * w1.z; acc[7] += zv * w1.w;
        }
        #pragma unroll
        for (int k = 0; k < 8; ++k) {
            const size_t idx = (size_t)(o0 + k) * HW + n0 + n;
            zg[idx] = gamma * acc[k] + xg[idx];
        }
    }
}

// ---------------- MFMA 3x3 conv (512->256) + BN + ReLU ----------------
// Implicit GEMM: 9 shifted 1x1 GEMMs; K = ci in chunks of 16.
// Block: 64 o x 128 px (2 image rows); 4 waves x 2 tiles of 32x32.
// Weights pre-transposed to bf16 [chunk][tap][o][ci16] in d_ws by wprep_convw.
__global__ __launch_bounds__(256) void conv_kernel(
    const unsigned short* __restrict__ wt,
    const float* __restrict__ bn_scale, const float* __restrict__ bn_bias,
    const float* __restrict__ bn_mean,  const float* __restrict__ bn_var,
    float* __restrict__ dout) {
    __shared__ __align__(16) unsigned short xl[4][66][CPAD];   // [row][col][ci] 10,560 B
    __shared__ __align__(16) unsigned short wl[9][64][CPAD];   // [tap][o][ci]  23,040 B

    const int pt = blockIdx.x;                       // 0..31 -> rows h0, h0+1
    const int ot = blockIdx.y;                       // 0..3
    const int b  = blockIdx.z;
    const int h0 = pt * 2;
    const int t  = threadIdx.x;
    const int w  = t >> 6, lane = t & 63, h = lane >> 5, l32 = lane & 31;
    const int osub = (w & 1) * 32;                   // wave's o sub-tile
    const int ps0  = (w >> 1) * 64;                  // wave's px subs: ps0, ps0+32

    // ---- precompute X staging geometry (ci-chunk independent) ----
    int ldsoff[9], srcoff[9]; bool valid[9], inb[9];
    #pragma unroll
    for (int k = 0; k < 9; ++k) {
        const int i = t + k * 256;
        valid[k] = i < 2112;                         // 4 rows * 66 cols * 8 ci-pairs
        const int col = i % 66, rem = i / 66;
        const int row = rem & 3, cp = rem >> 2;
        const int hh = h0 + row - 1, ww = col - 1;
        inb[k] = (hh >= 0 && hh < 64 && ww >= 0 && ww < 64);
        srcoff[k] = 2 * cp * HW + (inb[k] ? hh * 64 + ww : 0);
        ldsoff[k] = (row * 66 + col) * CPAD + 2 * cp;
    }
    unsigned short* xlf = &xl[0][0][0];

    // BN constants per accumulator register (D row = o via C/D formula)
    float inv[16], add[16];
    #pragma unroll
    for (int r = 0; r < 16; ++r) {
        const int o_g = ot * 64 + osub + (r & 3) + 8 * (r >> 2) + 4 * h;
        const float iv = bn_scale[o_g] * __frsqrt_rn(bn_var[o_g] + 1e-5f);
        inv[r] = iv;
        add[r] = bn_bias[o_g] - bn_mean[o_g] * iv;
    }

    v16f acc0, acc1;
    #pragma unroll
    for (int i = 0; i < 16; ++i) { acc0[i] = 0.f; acc1[i] = 0.f; }

    #pragma unroll 1
    for (int chunk = 0; chunk < 32; ++chunk) {
        const float* src = dout + O1_OFF + (size_t)(chunk < 16 ? 0 : 1) * 4194304
                         + (size_t)b * 1048576 + (size_t)((chunk & 15) * 16) * HW;
        const unsigned short* wsl = wt + (size_t)chunk * 36864 + (size_t)(ot * 64) * 16;
        __syncthreads();
        // ---- stage X: [row][col][ci], zero halo (coalesced fp32 reads) ----
        #pragma unroll
        for (int k = 0; k < 9; ++k) {
            if (valid[k]) {
                float v0 = 0.f, v1 = 0.f;
                if (inb[k]) {
                    const float* p = src + srcoff[k];
                    v0 = p[0]; v1 = p[HW];
                }
                *(unsigned*)&xlf[ldsoff[k]] = (unsigned)f2b(v0) | ((unsigned)f2b(v1) << 16);
            }
        }
        // ---- stage W: straight uint2 copy from pre-transposed bf16 ----
        #pragma unroll
        for (int u9 = 0; u9 < 9; ++u9) {
            const int u = t + u9 * 256;              // 0..2303
            const int tap = u >> 8, rem2 = u & 255;
            const int o = rem2 >> 2, q = rem2 & 3;
            const uint2 wv = *(const uint2*)(wsl + ((size_t)tap * 256 + o) * 16 + q * 4);
            *(uint2*)&wl[tap][o][q * 4] = wv;
        }
        __syncthreads();
        // ---- 9 taps x (K=16) MFMA ----
        #pragma unroll
        for (int dy = 0; dy < 3; ++dy) {
            #pragma unroll
            for (int dx = 0; dx < 3; ++dx) {
                const v8s af = load8(&wl[dy * 3 + dx][osub + l32][h * 8]);
                const int n0 = ps0 + l32, n1 = ps0 + 32 + l32;
                const v8s b0 = load8(&xl[(n0 >> 6) + dy][(n0 & 63) + dx][h * 8]);
                const v8s b1 = load8(&xl[(n1 >> 6) + dy][(n1 & 63) + dx][h * 8]);
                acc0 = __builtin_amdgcn_mfma_f32_32x32x16_bf16(af, b0, acc0, 0, 0, 0);
                acc1 = __builtin_amdgcn_mfma_f32_32x32x16_bf16(af, b1, acc1, 0, 0, 0);
            }
        }
    }
    // ---- epilogue: BN + ReLU + store ----
    const int px0 = ps0 + l32, px1 = ps0 + 32 + l32;
    const size_t gpx0 = (size_t)(h0 + (px0 >> 6)) * 64 + (px0 & 63);
    const size_t gpx1 = (size_t)(h0 + (px1 >> 6)) * 64 + (px1 & 63);
    #pragma unroll
    for (int r = 0; r < 16; ++r) {
        const int o_g = ot * 64 + osub + (r & 3) + 8 * (r >> 2) + 4 * h;
        const size_t obase = ((size_t)b * 256 + o_g) * HW;
        float v0 = acc0[r] * inv[r] + add[r];
        float v1 = acc1[r] * inv[r] + add[r];
        v0 = v0 > 0.f ? v0 : 0.f;
        v1 = v1 > 0.f ? v1 : 0.f;
        dout[obase + gpx0] = v0;
        dout[obase + gpx1] = v1;
    }
}

extern "C" void kernel_launch(void* const* d_in, const int* in_sizes, int n_in,
                              void* d_out, int out_size, void* d_ws, size_t ws_size,
                              hipStream_t stream) {
    (void)in_sizes; (void)n_in; (void)out_size; (void)ws_size;
    const float* x1   = (const float*)d_in[0];
    const float* x2   = (const float*)d_in[1];
    const float* wq1  = (const float*)d_in[2];
    const float* bq1  = (const float*)d_in[3];
    const float* wk1  = (const float*)d_in[4];
    const float* bk1  = (const float*)d_in[5];
    const float* wv1  = (const float*)d_in[6];
    const float* bv1  = (const float*)d_in[7];
    const float* wq2  = (const float*)d_in[8];
    const float* bq2  = (const float*)d_in[9];
    const float* wk2  = (const float*)d_in[10];
    const float* bk2  = (const float*)d_in[11];
    const float* wv2  = (const float*)d_in[12];
    const float* bv2  = (const float*)d_in[13];
    const float* gma  = (const float*)d_in[14];
    const float* wcat = (const float*)d_in[15];
    const float* bns  = (const float*)d_in[16];
    const float* bnb  = (const float*)d_in[17];
    const float* bnm  = (const float*)d_in[18];
    const float* bnv  = (const float*)d_in[19];

    float* out = (float*)d_out;
    unsigned short* wtc = (unsigned short*)d_ws;     // 2,359,296 B conv weights

    wprep_proj<<<704, 256, 0, stream>>>(wq1, wk1, wv1, wq2, wk2, wv2, out + WTP_OFF);
    wprep_convw<<<4608, 256, 0, stream>>>(wcat, wtc);
    proj_kernel<<<dim3(64, 2, 4), 256, 0, stream>>>(x1, x2, bq1, bk1, bq2, bk2, out);
    attn_kernel<<<dim3(64, 2, 4), 256, 0, stream>>>(x1, x2, out);
    mix_kernel<<<dim3(64, 2, 4), 256, 0, stream>>>(x1, x2, bv1, bv2, gma, out);
    conv_kernel<<<dim3(32, 4, 4), 256, 0, stream>>>(wtc, bns, bnb, bnm, bnv, out);
}

// Round 8
// 541.880 us; speedup vs baseline: 6.6755x; 1.3927x over previous
//
#include <hip/hip_runtime.h>
#include <hip/hip_bf16.h>

#define HW 4096

// ---------------- d_out layout ----------------
// bf16 elements:
//   [0         .. 1,048,576)  q_t [4][4096 n][64 c]   (c: 0..31 br1-q, 32..63 br2-q)
//   [1,048,576 .. 3,145,728)  k_t [2][4][4096 m][64 c]
// fp32 elements:
//   [1,572,864 .. 1,753,088)  wtp [2][256][352] transposed proj weights
//   [4,194,304 .. 8,388,608)  out1 (final, written by attn phase-2)
//   [8,388,608 .. 12,582,912) out2
// Scratch region [0..4,194,304 floats) is overwritten by conv output at the end.
// d_ws: wt_conv bf16 [32][9][256][16] = 2,359,296 B @ 0
//       wv_bf  bf16 [2][256 o][256 c] =   262,144 B @ 2,359,296
#define KT_OFF   1048576        // bf16 elements
#define WTP_OFF  1572864        // float elements
#define O1_OFF   4194304        // float elements
#define WVB_OFF  1179648        // bf16 elements into d_ws

typedef short v8s  __attribute__((ext_vector_type(8)));
typedef float v16f __attribute__((ext_vector_type(16)));

#define LSTR 72                 // attention LDS row stride (bf16)
#define ZSTR 264                // zt row stride (shorts): 528 B, 16B-aligned, bank-stride 33 (cf-free)
#define CPAD 20                 // conv LDS ci-stride (bf16)

__device__ __forceinline__ unsigned short f2b(float f) {   // fp32 -> bf16 RNE
    unsigned u = __float_as_uint(f);
    return (unsigned short)((u + 0x7fffu + ((u >> 16) & 1u)) >> 16);
}
__device__ __forceinline__ float b2f_raw(unsigned short u) {
    return __uint_as_float((unsigned)u << 16);
}
__device__ __forceinline__ void fma4(float4& a, float s, const float4& p) {
    a.x += s * p.x; a.y += s * p.y; a.z += s * p.z; a.w += s * p.w;
}
__device__ __forceinline__ v8s load8(const unsigned short* p) {  // 8 bf16 via two b64
    union { uint2 u[2]; v8s v; } t;
    t.u[0] = *(const uint2*)p;
    t.u[1] = *(const uint2*)(p + 4);
    return t.v;
}

// ---------------- weight prep: proj weights -> [sel][c][co(352)] fp32 ----------------
__global__ __launch_bounds__(256) void wprep_proj(
    const float* __restrict__ wq1, const float* __restrict__ wk1, const float* __restrict__ wv1,
    const float* __restrict__ wq2, const float* __restrict__ wk2, const float* __restrict__ wv2,
    float* __restrict__ wtp) {
    int idx = blockIdx.x * 256 + threadIdx.x;        // 2*256*352 = 180,224 total
    if (idx >= 2 * 256 * 352) return;
    int sel = idx / 90112;
    int r   = idx - sel * 90112;
    int c   = r / 352;
    int co  = r - c * 352;
    const float* w; int row;
    if (co < 32)      { w = sel ? wq2 : wq1; row = co; }
    else if (co < 96) { w = sel ? wk2 : wk1; row = co - 32; }
    else              { w = sel ? wv2 : wv1; row = co - 96; }
    wtp[idx] = w[row * 256 + c];
}

// ---------------- weight prep: conv w -> bf16 [chunk][tap][o][ci16] ----------------
__global__ __launch_bounds__(256) void wprep_convw(const float* __restrict__ wcat,
                                                   unsigned short* __restrict__ wt) {
    int i = blockIdx.x * 256 + threadIdx.x;          // 1,179,648 total
    if (i >= 32 * 9 * 256 * 16) return;
    const int ci_l = i & 15;
    const int o    = (i >> 4) & 255;
    const int t2   = i >> 12;
    const int tap  = t2 % 9;
    const int chunk = t2 / 9;
    wt[i] = f2b(wcat[((size_t)o * 512 + chunk * 16 + ci_l) * 9 + tap]);
}

// ---------------- weight prep: wv -> bf16 [2][o][c] ----------------
__global__ __launch_bounds__(256) void wprep_wv(const float* __restrict__ wv1,
                                                const float* __restrict__ wv2,
                                                unsigned short* __restrict__ out) {
    int i = blockIdx.x * 256 + threadIdx.x;          // 131,072 total
    if (i >= 131072) return;
    const float* src = (i < 65536) ? wv1 : wv2;
    out[i] = f2b(src[i & 65535]);
}

// ---------------- projections: q|k = W x + b -> bf16 transposed q_t/k_t ----------------
__global__ __launch_bounds__(256) void proj_kernel(
    const float* __restrict__ x1, const float* __restrict__ x2,
    const float* __restrict__ bq1, const float* __restrict__ bk1,
    const float* __restrict__ bq2, const float* __restrict__ bk2,
    float* __restrict__ dout) {
    __shared__ __align__(16) float xls[256][64];     // 64 KB
    const int tile = blockIdx.x, sel = blockIdx.y, b = blockIdx.z;
    const int n0 = tile * 64;
    const float* xb = (sel ? x2 : x1) + (size_t)b * 256 * HW;

    for (int i = threadIdx.x; i < 4096; i += 256) {
        const int row = i >> 4, c4 = (i & 15) * 4;
        *(float4*)&xls[row][c4] = *(const float4*)(xb + (size_t)row * HW + n0 + c4);
    }
    __syncthreads();

    const int n   = threadIdx.x & 63;
    const int cog = __builtin_amdgcn_readfirstlane(threadIdx.x >> 6);   // 0..3, wave-uniform
    const float* bq = sel ? bq2 : bq1;
    const float* bk = sel ? bk2 : bk1;
    const float* wc = dout + WTP_OFF + (size_t)sel * 90112;   // [c][352]
    unsigned short* qtg = (unsigned short*)dout + (size_t)b * HW * 64;
    unsigned short* ktg = (unsigned short*)dout + KT_OFF + (size_t)(sel * 4 + b) * HW * 64;

    for (int blk = 0; blk < 3; ++blk) {              // 4 groups * 24 co = 96
        const int co0 = cog * 24 + blk * 8;          // never straddles the q/k split at 32
        float acc[8];
        const float* brow; int r0; bool isq;
        if (co0 < 32) { r0 = co0;      brow = bq; isq = true;  }
        else          { r0 = co0 - 32; brow = bk; isq = false; }
        #pragma unroll
        for (int k = 0; k < 8; ++k) acc[k] = brow[r0 + k];
        #pragma unroll 4
        for (int c = 0; c < 256; ++c) {
            const float xv = xls[c][n];
            const float4 w0 = *(const float4*)(wc + (size_t)c * 352 + co0);
            const float4 w1 = *(const float4*)(wc + (size_t)c * 352 + co0 + 4);
            acc[0] += xv * w0.x; acc[1] += xv * w0.y; acc[2] += xv * w0.z; acc[3] += xv * w0.w;
            acc[4] += xv * w1.x; acc[5] += xv * w1.y; acc[6] += xv * w1.z; acc[7] += xv * w1.w;
        }
        unsigned short pk[8];
        #pragma unroll
        for (int k = 0; k < 8; ++k) pk[k] = f2b(acc[k]);
        unsigned short* dst = isq ? (qtg + (size_t)(n0 + n) * 64 + sel * 32 + r0)
                                  : (ktg + (size_t)(n0 + n) * 64 + r0);
        *(uint4*)dst = *(const uint4*)pk;            // 16B store
    }
}

// ---------------- MFMA attention + fused mix ----------------
// Phase 1: S=Q^T K, P=exp(S), zacc = X P  (64 m-tiles)
// Phase 2: out = gamma * (Wv (zacc/l) + bv) + x   (z kept on-chip in LDS)
__global__ __launch_bounds__(256, 2) void attn_kernel(
    const float* __restrict__ in1, const float* __restrict__ in2,
    const unsigned short* __restrict__ wvbf,         // [2][256 o][256 c] bf16
    const float* __restrict__ bv1, const float* __restrict__ bv2,
    const float* __restrict__ gamma_p,
    float* __restrict__ dout) {
    __shared__ __align__(16) unsigned short qlds[64][LSTR];    // [n][c]
    __shared__ __align__(16) unsigned short klds[64][LSTR];    // [m][c]
    __shared__ __align__(16) unsigned short plds[64][LSTR];    // [n][m]
    __shared__ __align__(16) unsigned short xlds[256][LSTR];   // [c][m]; reused as zt in phase 2
    __shared__ float lsum[64][4];
    __shared__ float lfin[64];

    const int qt = blockIdx.x, br = blockIdx.y, b = blockIdx.z;
    const int t = threadIdx.x;
    const int w = t >> 6, lane = t & 63, h = lane >> 5, l32 = lane & 31;

    const unsigned short* qtg = (const unsigned short*)dout + (size_t)b * HW * 64;
    const unsigned short* ktg = (const unsigned short*)dout + KT_OFF + (size_t)(br * 4 + b) * HW * 64;
    const float* xg = (br ? in2 : in1) + (size_t)b * 256 * HW;
    float* zo = dout + O1_OFF + (size_t)br * 4194304 + (size_t)b * 256 * HW;

    for (int i = t; i < 512; i += 256) {
        const int row = i >> 3, c8 = (i & 7) * 8;
        *(uint4*)&qlds[row][c8] = *(const uint4*)(qtg + (size_t)(qt * 64 + row) * 64 + c8);
    }

    const int nsub = (w & 1) * 32, msub = (w >> 1) * 32;
    const int c0 = w * 64;
    const int koff = h * 8;

    v16f a00, a01, a10, a11;
    #pragma unroll
    for (int i = 0; i < 16; ++i) { a00[i] = 0.f; a01[i] = 0.f; a10[i] = 0.f; a11[i] = 0.f; }
    float lrun = 0.f;
    const int nl2 = t >> 2, q16 = (t & 3) * 16;

    uint4  kreg[2];
    float4 xreg[16];
    #pragma unroll
    for (int j = 0; j < 2; ++j) {
        const int i = t + j * 256, row = i >> 3, c8 = (i & 7) * 8;
        kreg[j] = *(const uint4*)(ktg + (size_t)row * 64 + c8);
    }
    #pragma unroll
    for (int j = 0; j < 16; ++j) {
        const int i = t + j * 256, c = i >> 4, m4 = (i & 15) * 4;
        xreg[j] = *(const float4*)(xg + (size_t)c * HW + m4);
    }

    #pragma unroll 1
    for (int mt = 0; mt < 64; ++mt) {
        __syncthreads();
        #pragma unroll
        for (int j = 0; j < 2; ++j) {
            const int i = t + j * 256, row = i >> 3, c8 = (i & 7) * 8;
            *(uint4*)&klds[row][c8] = kreg[j];
        }
        #pragma unroll
        for (int j = 0; j < 16; ++j) {
            const int i = t + j * 256, c = i >> 4, m4 = (i & 15) * 4;
            uint2 pk;
            pk.x = (unsigned)f2b(xreg[j].x) | ((unsigned)f2b(xreg[j].y) << 16);
            pk.y = (unsigned)f2b(xreg[j].z) | ((unsigned)f2b(xreg[j].w) << 16);
            *(uint2*)&xlds[c][m4] = pk;
        }
        __syncthreads();
        v16f s;
        #pragma unroll
        for (int i = 0; i < 16; ++i) s[i] = 0.f;
        #pragma unroll
        for (int ks = 0; ks < 4; ++ks) {
            const v8s aq = *(const v8s*)&qlds[nsub + l32][ks * 16 + koff];
            const v8s bk = *(const v8s*)&klds[msub + l32][ks * 16 + koff];
            s = __builtin_amdgcn_mfma_f32_32x32x16_bf16(aq, bk, s, 0, 0, 0);
        }
        #pragma unroll
        for (int r = 0; r < 16; ++r) {
            const int nl = nsub + (r & 3) + 8 * (r >> 2) + 4 * h;
            const int ml = msub + l32;
            const float e = __expf(fminf(fmaxf(s[r], -30.f), 30.f));
            plds[nl][ml] = f2b(e);
        }
        if (mt < 63) {
            const int mg = (mt + 1) * 64;
            #pragma unroll
            for (int j = 0; j < 2; ++j) {
                const int i = t + j * 256, row = i >> 3, c8 = (i & 7) * 8;
                kreg[j] = *(const uint4*)(ktg + (size_t)(mg + row) * 64 + c8);
            }
            #pragma unroll
            for (int j = 0; j < 16; ++j) {
                const int i = t + j * 256, c = i >> 4, m4 = (i & 15) * 4;
                xreg[j] = *(const float4*)(xg + (size_t)c * HW + mg + m4);
            }
        }
        __syncthreads();
        {
            const v8s r0 = *(const v8s*)&plds[nl2][q16];
            const v8s r1 = *(const v8s*)&plds[nl2][q16 + 8];
            float su = 0.f;
            #pragma unroll
            for (int e = 0; e < 8; ++e)
                su += b2f_raw((unsigned short)r0[e]) + b2f_raw((unsigned short)r1[e]);
            lrun += su;
        }
        #pragma unroll
        for (int ks = 0; ks < 4; ++ks) {
            const int mo = ks * 16 + koff;
            const v8s xa0 = *(const v8s*)&xlds[c0 + l32][mo];
            const v8s xa1 = *(const v8s*)&xlds[c0 + 32 + l32][mo];
            const v8s pb0 = *(const v8s*)&plds[l32][mo];
            const v8s pb1 = *(const v8s*)&plds[32 + l32][mo];
            a00 = __builtin_amdgcn_mfma_f32_32x32x16_bf16(xa0, pb0, a00, 0, 0, 0);
            a01 = __builtin_amdgcn_mfma_f32_32x32x16_bf16(xa0, pb1, a01, 0, 0, 0);
            a10 = __builtin_amdgcn_mfma_f32_32x32x16_bf16(xa1, pb0, a10, 0, 0, 0);
            a11 = __builtin_amdgcn_mfma_f32_32x32x16_bf16(xa1, pb1, a11, 0, 0, 0);
        }
    }
    // ---- softmax denominators ----
    __syncthreads();
    lsum[nl2][t & 3] = lrun;
    __syncthreads();
    if (t < 64) lfin[t] = 1.0f / (lsum[t][0] + lsum[t][1] + lsum[t][2] + lsum[t][3]);
    __syncthreads();
    const float rl0 = lfin[l32];
    const float rl1 = lfin[32 + l32];
    // ---- normalized z -> LDS zt[n][c] bf16 (overlay on xlds; conflict-free stride) ----
    unsigned short (*zt)[ZSTR] = (unsigned short (*)[ZSTR])&xlds[0][0];
    #pragma unroll
    for (int r = 0; r < 16; ++r) {
        const int c = c0 + (r & 3) + 8 * (r >> 2) + 4 * h;
        zt[l32][c]           = f2b(a00[r] * rl0);
        zt[32 + l32][c]      = f2b(a01[r] * rl1);
        zt[l32][c + 32]      = f2b(a10[r] * rl0);
        zt[32 + l32][c + 32] = f2b(a11[r] * rl1);
    }
    __syncthreads();
    // ---- phase 2: out[o][n] = gamma * (Wv z + bv) + x ----
    const unsigned short* wvb = wvbf + (size_t)br * 65536;   // [o][c] bf16
    const float* bvp = br ? bv2 : bv1;
    const float gamma = gamma_p[0];
    const int ob = w * 64;
    const int ncol = qt * 64;
    v16f m00, m01, m10, m11;
    #pragma unroll
    for (int i = 0; i < 16; ++i) { m00[i] = 0.f; m01[i] = 0.f; m10[i] = 0.f; m11[i] = 0.f; }
    #pragma unroll
    for (int ks = 0; ks < 16; ++ks) {
        const int k = ks * 16 + koff;
        const v8s aA = load8(wvb + (size_t)(ob + l32) * 256 + k);
        const v8s aB = load8(wvb + (size_t)(ob + 32 + l32) * 256 + k);
        const v8s b0v = *(const v8s*)&zt[l32][k];
        const v8s b1v = *(const v8s*)&zt[32 + l32][k];
        m00 = __builtin_amdgcn_mfma_f32_32x32x16_bf16(aA, b0v, m00, 0, 0, 0);
        m01 = __builtin_amdgcn_mfma_f32_32x32x16_bf16(aA, b1v, m01, 0, 0, 0);
        m10 = __builtin_amdgcn_mfma_f32_32x32x16_bf16(aB, b0v, m10, 0, 0, 0);
        m11 = __builtin_amdgcn_mfma_f32_32x32x16_bf16(aB, b1v, m11, 0, 0, 0);
    }
    #pragma unroll
    for (int r = 0; r < 16; ++r) {
        const int o = ob + (r & 3) + 8 * (r >> 2) + 4 * h;
        const float bvA = bvp[o], bvB = bvp[o + 32];
        const size_t base0 = (size_t)o * HW + ncol;
        const size_t base1 = (size_t)(o + 32) * HW + ncol;
        zo[base0 + l32]      = gamma * (m00[r] + bvA) + xg[base0 + l32];
        zo[base0 + 32 + l32] = gamma * (m01[r] + bvA) + xg[base0 + 32 + l32];
        zo[base1 + l32]      = gamma * (m10[r] + bvB) + xg[base1 + l32];
        zo[base1 + 32 + l32] = gamma * (m11[r] + bvB) + xg[base1 + 32 + l32];
    }
}

// ---------------- MFMA 3x3 conv (512->256) + BN + ReLU ----------------
__global__ __launch_bounds__(256) void conv_kernel(
    const unsigned short* __restrict__ wt,
    const float* __restrict__ bn_scale, const float* __restrict__ bn_bias,
    const float* __restrict__ bn_mean,  const float* __restrict__ bn_var,
    float* __restrict__ dout) {
    __shared__ __align__(16) unsigned short xl[4][66][CPAD];   // 10,560 B
    __shared__ __align__(16) unsigned short wl[9][64][CPAD];   // 23,040 B

    const int pt = blockIdx.x;                       // 0..31 -> rows h0, h0+1
    const int ot = blockIdx.y;                       // 0..3
    const int b  = blockIdx.z;
    const int h0 = pt * 2;
    const int t  = threadIdx.x;
    const int w  = t >> 6, lane = t & 63, h = lane >> 5, l32 = lane & 31;
    const int osub = (w & 1) * 32;
    const int ps0  = (w >> 1) * 64;

    int ldsoff[9], srcoff[9]; bool valid[9], inb[9];
    #pragma unroll
    for (int k = 0; k < 9; ++k) {
        const int i = t + k * 256;
        valid[k] = i < 2112;
        const int col = i % 66, rem = i / 66;
        const int row = rem & 3, cp = rem >> 2;
        const int hh = h0 + row - 1, ww = col - 1;
        inb[k] = (hh >= 0 && hh < 64 && ww >= 0 && ww < 64);
        srcoff[k] = 2 * cp * HW + (inb[k] ? hh * 64 + ww : 0);
        ldsoff[k] = (row * 66 + col) * CPAD + 2 * cp;
    }
    unsigned short* xlf = &xl[0][0][0];

    float inv[16], add[16];
    #pragma unroll
    for (int r = 0; r < 16; ++r) {
        const int o_g = ot * 64 + osub + (r & 3) + 8 * (r >> 2) + 4 * h;
        const float iv = bn_scale[o_g] * __frsqrt_rn(bn_var[o_g] + 1e-5f);
        inv[r] = iv;
        add[r] = bn_bias[o_g] - bn_mean[o_g] * iv;
    }

    v16f acc0, acc1;
    #pragma unroll
    for (int i = 0; i < 16; ++i) { acc0[i] = 0.f; acc1[i] = 0.f; }

    #pragma unroll 1
    for (int chunk = 0; chunk < 32; ++chunk) {
        const float* src = dout + O1_OFF + (size_t)(chunk < 16 ? 0 : 1) * 4194304
                         + (size_t)b * 1048576 + (size_t)((chunk & 15) * 16) * HW;
        const unsigned short* wsl = wt + (size_t)chunk * 36864 + (size_t)(ot * 64) * 16;
        __syncthreads();
        #pragma unroll
        for (int k = 0; k < 9; ++k) {
            if (valid[k]) {
                float v0 = 0.f, v1 = 0.f;
                if (inb[k]) {
                    const float* p = src + srcoff[k];
                    v0 = p[0]; v1 = p[HW];
                }
                *(unsigned*)&xlf[ldsoff[k]] = (unsigned)f2b(v0) | ((unsigned)f2b(v1) << 16);
            }
        }
        #pragma unroll
        for (int u9 = 0; u9 < 9; ++u9) {
            const int u = t + u9 * 256;
            const int tap = u >> 8, rem2 = u & 255;
            const int o = rem2 >> 2, q = rem2 & 3;
            const uint2 wv = *(const uint2*)(wsl + ((size_t)tap * 256 + o) * 16 + q * 4);
            *(uint2*)&wl[tap][o][q * 4] = wv;
        }
        __syncthreads();
        #pragma unroll
        for (int dy = 0; dy < 3; ++dy) {
            #pragma unroll
            for (int dx = 0; dx < 3; ++dx) {
                const v8s af = load8(&wl[dy * 3 + dx][osub + l32][h * 8]);
                const int n0 = ps0 + l32, n1 = ps0 + 32 + l32;
                const v8s b0 = load8(&xl[(n0 >> 6) + dy][(n0 & 63) + dx][h * 8]);
                const v8s b1 = load8(&xl[(n1 >> 6) + dy][(n1 & 63) + dx][h * 8]);
                acc0 = __builtin_amdgcn_mfma_f32_32x32x16_bf16(af, b0, acc0, 0, 0, 0);
                acc1 = __builtin_amdgcn_mfma_f32_32x32x16_bf16(af, b1, acc1, 0, 0, 0);
            }
        }
    }
    const int px0 = ps0 + l32, px1 = ps0 + 32 + l32;
    const size_t gpx0 = (size_t)(h0 + (px0 >> 6)) * 64 + (px0 & 63);
    const size_t gpx1 = (size_t)(h0 + (px1 >> 6)) * 64 + (px1 & 63);
    #pragma unroll
    for (int r = 0; r < 16; ++r) {
        const int o_g = ot * 64 + osub + (r & 3) + 8 * (r >> 2) + 4 * h;
        const size_t obase = ((size_t)b * 256 + o_g) * HW;
        float v0 = acc0[r] * inv[r] + add[r];
        float v1 = acc1[r] * inv[r] + add[r];
        v0 = v0 > 0.f ? v0 : 0.f;
        v1 = v1 > 0.f ? v1 : 0.f;
        dout[obase + gpx0] = v0;
        dout[obase + gpx1] = v1;
    }
}

extern "C" void kernel_launch(void* const* d_in, const int* in_sizes, int n_in,
                              void* d_out, int out_size, void* d_ws, size_t ws_size,
                              hipStream_t stream) {
    (void)in_sizes; (void)n_in; (void)out_size; (void)ws_size;
    const float* x1   = (const float*)d_in[0];
    const float* x2   = (const float*)d_in[1];
    const float* wq1  = (const float*)d_in[2];
    const float* bq1  = (const float*)d_in[3];
    const float* wk1  = (const float*)d_in[4];
    const float* bk1  = (const float*)d_in[5];
    const float* wv1  = (const float*)d_in[6];
    const float* bv1  = (const float*)d_in[7];
    const float* wq2  = (const float*)d_in[8];
    const float* bq2  = (const float*)d_in[9];
    const float* wk2  = (const float*)d_in[10];
    const float* bk2  = (const float*)d_in[11];
    const float* wv2  = (const float*)d_in[12];
    const float* bv2  = (const float*)d_in[13];
    const float* gma  = (const float*)d_in[14];
    const float* wcat = (const float*)d_in[15];
    const float* bns  = (const float*)d_in[16];
    const float* bnb  = (const float*)d_in[17];
    const float* bnm  = (const float*)d_in[18];
    const float* bnv  = (const float*)d_in[19];

    float* out = (float*)d_out;
    unsigned short* wtc = (unsigned short*)d_ws;     // conv weights bf16
    unsigned short* wvb = wtc + WVB_OFF;             // wv bf16 [2][256][256]

    wprep_proj<<<704, 256, 0, stream>>>(wq1, wk1, wv1, wq2, wk2, wv2, out + WTP_OFF);
    wprep_convw<<<4608, 256, 0, stream>>>(wcat, wtc);
    wprep_wv<<<512, 256, 0, stream>>>(wv1, wv2, wvb);
    proj_kernel<<<dim3(64, 2, 4), 256, 0, stream>>>(x1, x2, bq1, bk1, bq2, bk2, out);
    attn_kernel<<<dim3(64, 2, 4), 256, 0, stream>>>(x1, x2, wvb, bv1, bv2, gma, out);
    conv_kernel<<<dim3(32, 4, 4), 256, 0, stream>>>(wtc, bns, bnb, bnm, bnv, out);
}